// Round 2
// baseline (7442.914 us; speedup 1.0000x reference)
//
#include <hip/hip_runtime.h>
#include <hip/hip_bf16.h>
#include <cstdint>

constexpr int CL = 12, CH = 12, CD = 768, CP = 20, CNT = 197, CNF = 217, CB = 64, CNCLS = 100;
constexpr float CSCALE = 0.125f;

typedef __bf16 bf16x8 __attribute__((ext_vector_type(8)));
typedef float f32x4 __attribute__((ext_vector_type(4)));
typedef short short4v __attribute__((ext_vector_type(4)));

__device__ __forceinline__ short f2b(float f){
  uint32_t x = __builtin_bit_cast(uint32_t, f);
  x = (x + 0x7fffu + ((x >> 16) & 1u)) >> 16;
  return (short)x;
}
__device__ __forceinline__ float b2f(short s){
  return __builtin_bit_cast(float, ((uint32_t)(uint16_t)s) << 16);
}
__device__ __forceinline__ void gload_lds16(const short* g, short* l){
  __builtin_amdgcn_global_load_lds((const __attribute__((address_space(1))) void*)g,
                                   (__attribute__((address_space(3))) void*)l, 16, 0, 0);
}

// ---------------- GEMM: C[M,N] = A[M,K](bf16) * Bt[N,K]^T(bf16) + bias, epilogues ----
// EPI 0: bias -> bf16 store; 1: bias+gelu -> bf16; 2: bias + add into fp32 Cf; 3: patch (bias+pos -> Cf remapped rows)
template<int EPI>
__global__ __launch_bounds__(256, 2) void gemm_bt(
    const short* __restrict__ A, const short* __restrict__ Bt,
    const float* __restrict__ bias, short* __restrict__ Cb,
    float* __restrict__ Cf, const float* __restrict__ pos,
    int M, int N, int K)
{
  __shared__ short As[128 * 32];
  __shared__ short Bs[128 * 32];
  const int tid = threadIdx.x;
  const int wave = tid >> 6, lane = tid & 63;
  const int m0 = blockIdx.x * 128, n0 = blockIdx.y * 128;
  const int wr = wave >> 1, wc = wave & 1;
  const int lrow = lane & 15, lk = lane >> 4;

  f32x4 zf = {0.f, 0.f, 0.f, 0.f};
  f32x4 acc[4][4];
  #pragma unroll
  for (int i = 0; i < 4; i++)
    #pragma unroll
    for (int j = 0; j < 4; j++) acc[i][j] = zf;

  for (int k0 = 0; k0 < K; k0 += 32) {
    __syncthreads();
    #pragma unroll
    for (int i = 0; i < 2; i++) {
      int idx = i * 256 + tid;
      int row = idx >> 2, c8 = (idx & 3) * 8;
      int gra = m0 + row; gra = gra < M ? gra : M - 1;
      gload_lds16(A + (size_t)gra * K + k0 + c8, (short*)((char*)As + (i * 256 + wave * 64) * 16));
      int grb = n0 + row;
      gload_lds16(Bt + (size_t)grb * K + k0 + c8, (short*)((char*)Bs + (i * 256 + wave * 64) * 16));
    }
    __syncthreads();
    const short* pA = As + (wr * 64 + lrow) * 32 + lk * 8;
    const short* pB = Bs + (wc * 64 + lrow) * 32 + lk * 8;
    bf16x8 af[4], bfv[4];
    #pragma unroll
    for (int mi = 0; mi < 4; mi++) af[mi] = *(const bf16x8*)(pA + mi * 16 * 32);
    #pragma unroll
    for (int ni = 0; ni < 4; ni++) bfv[ni] = *(const bf16x8*)(pB + ni * 16 * 32);
    #pragma unroll
    for (int mi = 0; mi < 4; mi++)
      #pragma unroll
      for (int ni = 0; ni < 4; ni++)
        acc[mi][ni] = __builtin_amdgcn_mfma_f32_16x16x32_bf16(af[mi], bfv[ni], acc[mi][ni], 0, 0, 0);
  }

  #pragma unroll
  for (int mi = 0; mi < 4; mi++) {
    int rbase = m0 + wr * 64 + mi * 16 + lk * 4;
    #pragma unroll
    for (int ni = 0; ni < 4; ni++) {
      int col = n0 + wc * 64 + ni * 16 + lrow;
      float bv = bias[col];
      f32x4 v = acc[mi][ni];
      #pragma unroll
      for (int r = 0; r < 4; r++) {
        int row = rbase + r;
        if (row >= M) continue;
        float val = v[r] + bv;
        if constexpr (EPI == 0) {
          Cb[(size_t)row * N + col] = f2b(val);
        } else if constexpr (EPI == 1) {
          float g = 0.5f * val * (1.0f + erff(val * 0.70710678118f));
          Cb[(size_t)row * N + col] = f2b(g);
        } else if constexpr (EPI == 2) {
          Cf[(size_t)row * N + col] += val;
        } else {
          int b = row / 196, pp = row % 196;
          Cf[((size_t)(b * CNT + 1 + pp)) * CD + col] = val + pos[(1 + pp) * CD + col];
        }
      }
    }
  }
}

// ---------------- weight transpose + bf16 convert: in[K,N] f32 -> out[N,K] bf16 ------
__global__ void wtrans(const float* __restrict__ in, short* __restrict__ out, int K, int N)
{
  __shared__ float t[32][33];
  int tx = threadIdx.x, ty = threadIdx.y;
  int k0 = blockIdx.x * 32, n0 = blockIdx.y * 32;
  for (int i = ty; i < 32; i += 8)
    t[i][tx] = in[(size_t)(k0 + i) * N + n0 + tx];
  __syncthreads();
  for (int i = ty; i < 32; i += 8)
    out[(size_t)(n0 + i) * K + k0 + tx] = f2b(t[tx][i]);
}

// ---------------- patch matrix build: x[B,3,224,224] -> Pm[B*196, 768] bf16 ---------
__global__ void patch_build(const float* __restrict__ x, short* __restrict__ Pm)
{
  int idx = blockIdx.x * 256 + threadIdx.x;   // < 12544*768
  int r = idx / 768, c = idx % 768;
  int b = r / 196, np = r % 196;
  int gy = np / 14, gx = np % 14;
  int ch = c >> 8, rem = c & 255, py = rem >> 4, px = rem & 15;
  float v = x[((size_t)(b * 3 + ch) * 224 + gy * 16 + py) * 224 + gx * 16 + px];
  Pm[idx] = f2b(v);
}

__global__ void cls_pos(const float* __restrict__ cls, const float* __restrict__ pos, float* __restrict__ h)
{
  int idx = blockIdx.x * 256 + threadIdx.x;   // < 64*768
  int b = idx / 768, c = idx % 768;
  h[(size_t)(b * CNT) * CD + c] = cls[c] + pos[c];
}

// ---------------- FFT(prompts) real part, separable, all layers --------------------
__global__ __launch_bounds__(256) void fft_stage1(const float* __restrict__ prompts,
                                                  float* __restrict__ Cc, float* __restrict__ Ss)
{
  __shared__ float xr[768], ct[768], st[768];
  int blk = blockIdx.x;                       // layer*20 + p
  const float* src = prompts + (size_t)blk * 768;
  for (int c = threadIdx.x; c < 768; c += 256) {
    xr[c] = src[c];
    float ang = (float)c * (6.2831853071795864f / 768.f);
    float sv, cv; sincosf(ang, &sv, &cv);
    ct[c] = cv; st[c] = sv;
  }
  __syncthreads();
  for (int k = threadIdx.x; k < 768; k += 256) {
    float cs = 0.f, sn = 0.f; int idx = 0;
    for (int d = 0; d < 768; d++) {
      float xv = xr[d];
      cs += xv * ct[idx];
      sn += xv * st[idx];
      idx += k; if (idx >= 768) idx -= 768;
    }
    Cc[(size_t)blk * 768 + k] = cs;
    Ss[(size_t)blk * 768 + k] = sn;
  }
}

__global__ __launch_bounds__(256) void fft_stage2(const float* __restrict__ Cc, const float* __restrict__ Ss,
                                                  float* __restrict__ pr)
{
  int blk = blockIdx.x; int layer = blk / 20, q = blk % 20;
  __shared__ float tc[20], tsn[20];
  if (threadIdx.x < 20) {
    int j = threadIdx.x;
    float ang = (float)((q * j) % 20) * (6.2831853071795864f / 20.f);
    float sv, cv; sincosf(ang, &sv, &cv);
    tc[j] = cv; tsn[j] = sv;
  }
  __syncthreads();
  for (int k = threadIdx.x; k < 768; k += 256) {
    float acc = 0.f;
    #pragma unroll
    for (int p2 = 0; p2 < 20; p2++) {
      size_t off = ((size_t)(layer * 20 + p2)) * 768 + k;
      acc += Cc[off] * tc[p2] - Ss[off] * tsn[p2];
    }
    pr[((size_t)(layer * 20 + q)) * 768 + k] = acc;
  }
}

// ---------------- LayerNorms ------------------------------------------------------
__global__ __launch_bounds__(256) void ln1_kernel(
    const float* __restrict__ h, const float* __restrict__ pr,
    const float* __restrict__ g, const float* __restrict__ bb,
    short* __restrict__ outp)
{
  int wave = threadIdx.x >> 6, lane = threadIdx.x & 63;
  int row = blockIdx.x * 4 + wave;            // < 13888
  int b = row / CNF, t = row % CNF;
  const float* src;
  if (t == 0) src = h + (size_t)(b * CNT) * CD;
  else if (t <= CP) src = pr + (size_t)(t - 1) * CD;
  else src = h + (size_t)(b * CNT + (t - CP)) * CD;
  float4 v[3];
  float s = 0.f, sq = 0.f;
  #pragma unroll
  for (int j = 0; j < 3; j++) {
    v[j] = *(const float4*)(src + (lane + 64 * j) * 4);
    s += v[j].x + v[j].y + v[j].z + v[j].w;
    sq += v[j].x * v[j].x + v[j].y * v[j].y + v[j].z * v[j].z + v[j].w * v[j].w;
  }
  #pragma unroll
  for (int m = 1; m < 64; m <<= 1) { s += __shfl_xor(s, m); sq += __shfl_xor(sq, m); }
  float mean = s * (1.f / 768.f);
  float var = sq * (1.f / 768.f) - mean * mean;
  float rs = rsqrtf(var + 1e-6f);
  short* orow = outp + (size_t)row * CD;
  #pragma unroll
  for (int j = 0; j < 3; j++) {
    int c = (lane + 64 * j) * 4;
    float4 gg = *(const float4*)(g + c);
    float4 bv = *(const float4*)(bb + c);
    short4v o;
    o.x = f2b((v[j].x - mean) * rs * gg.x + bv.x);
    o.y = f2b((v[j].y - mean) * rs * gg.y + bv.y);
    o.z = f2b((v[j].z - mean) * rs * gg.z + bv.z);
    o.w = f2b((v[j].w - mean) * rs * gg.w + bv.w);
    *(short4v*)(orow + c) = o;
  }
}

__global__ __launch_bounds__(256) void ln2_kernel(
    const float* __restrict__ h, const float* __restrict__ g, const float* __restrict__ bb,
    short* __restrict__ outp)
{
  int wave = threadIdx.x >> 6, lane = threadIdx.x & 63;
  int row = blockIdx.x * 4 + wave;            // < 12608
  const float* src = h + (size_t)row * CD;
  float4 v[3];
  float s = 0.f, sq = 0.f;
  #pragma unroll
  for (int j = 0; j < 3; j++) {
    v[j] = *(const float4*)(src + (lane + 64 * j) * 4);
    s += v[j].x + v[j].y + v[j].z + v[j].w;
    sq += v[j].x * v[j].x + v[j].y * v[j].y + v[j].z * v[j].z + v[j].w * v[j].w;
  }
  #pragma unroll
  for (int m = 1; m < 64; m <<= 1) { s += __shfl_xor(s, m); sq += __shfl_xor(sq, m); }
  float mean = s * (1.f / 768.f);
  float var = sq * (1.f / 768.f) - mean * mean;
  float rs = rsqrtf(var + 1e-6f);
  short* orow = outp + (size_t)row * CD;
  #pragma unroll
  for (int j = 0; j < 3; j++) {
    int c = (lane + 64 * j) * 4;
    float4 gg = *(const float4*)(g + c);
    float4 bv = *(const float4*)(bb + c);
    short4v o;
    o.x = f2b((v[j].x - mean) * rs * gg.x + bv.x);
    o.y = f2b((v[j].y - mean) * rs * gg.y + bv.y);
    o.z = f2b((v[j].z - mean) * rs * gg.z + bv.z);
    o.w = f2b((v[j].w - mean) * rs * gg.w + bv.w);
    *(short4v*)(orow + c) = o;
  }
}

// ---------------- fused attention: per (b,h), QK^T -> softmax*mask -> PV (MFMA) ----
__global__ __launch_bounds__(256, 1) void attn_kernel(
    const short* __restrict__ qkv, const float* __restrict__ aw,
    const float* __restrict__ ab, const float* __restrict__ mask,
    short* __restrict__ o)
{
  __shared__ short Ks[224 * 72];       // keys as B^T [key][d], row stride 72 (144B, 16B-mult)
  __shared__ short Vt[64 * 232];       // V^T [d][token], row stride 232 (464B)
  __shared__ short Ps[4][32 * 232];    // per-wave P tile [32 q][224 k]
  __shared__ float ms[224];
  const int hh = blockIdx.x, b = blockIdx.y, z = blockIdx.z;
  const int tid = threadIdx.x, wave = tid >> 6, lane = tid & 63;
  const int lrow = lane & 15, lk = lane >> 4;

  for (int t = tid; t < 224; t += 256) ms[t] = (t < CNF) ? mask[t] : 0.f;
  for (int idx = tid; idx < 224 * 8; idx += 256) {
    int t = idx >> 3, c8 = (idx & 7) * 8;
    uint4 val = {0u, 0u, 0u, 0u};
    if (t < CNF) val = *(const uint4*)(qkv + ((size_t)(b * CNF + t)) * 2304 + 768 + hh * 64 + c8);
    *(uint4*)&Ks[t * 72 + c8] = val;
  }
  for (int idx = tid; idx < 224 * 64; idx += 256) {
    int t = idx >> 6, d = idx & 63;
    float v = 0.f;
    if (t < CNF) {
      v = b2f(qkv[((size_t)(b * CNF + t)) * 2304 + 1536 + hh * 64 + d]);
      if (t >= 1 && t <= CP) {
        int c = hh * 64 + d;
        v = v * aw[(t - 1) * CD + c] + ab[(t - 1) * CD + c];
      }
    }
    Vt[d * 232 + t] = f2b(v);
  }
  __syncthreads();

  const int qt = z * 4 + wave;     // 0..7 (tile 7 computes garbage, stores masked)
  const int q0 = qt * 32;
  bf16x8 aq[2][2];
  #pragma unroll
  for (int mi = 0; mi < 2; mi++)
    #pragma unroll
    for (int ks = 0; ks < 2; ks++) {
      int t = q0 + mi * 16 + lrow; if (t > CNF - 1) t = CNF - 1;
      aq[mi][ks] = *(const bf16x8*)(qkv + ((size_t)(b * CNF + t)) * 2304 + hh * 64 + ks * 32 + lk * 8);
    }

  f32x4 zf = {0.f, 0.f, 0.f, 0.f};
  f32x4 s[2][14];
  #pragma unroll
  for (int mi = 0; mi < 2; mi++)
    #pragma unroll
    for (int nf = 0; nf < 14; nf++) s[mi][nf] = zf;

  #pragma unroll
  for (int ks = 0; ks < 2; ks++)
    #pragma unroll
    for (int nf = 0; nf < 14; nf++) {
      bf16x8 bk = *(const bf16x8*)&Ks[(nf * 16 + lrow) * 72 + ks * 32 + lk * 8];
      s[0][nf] = __builtin_amdgcn_mfma_f32_16x16x32_bf16(aq[0][ks], bk, s[0][nf], 0, 0, 0);
      s[1][nf] = __builtin_amdgcn_mfma_f32_16x16x32_bf16(aq[1][ks], bk, s[1][nf], 0, 0, 0);
    }

  short* Pw = Ps[wave];
  #pragma unroll
  for (int mi = 0; mi < 2; mi++)
    #pragma unroll
    for (int r = 0; r < 4; r++) {
      float tv[14];
      float mx = -3.4e38f;
      #pragma unroll
      for (int nf = 0; nf < 14; nf++) {
        int col = nf * 16 + lrow;
        float xx = s[mi][nf][r] * CSCALE;
        tv[nf] = xx;
        if (col < CNF && xx > mx) mx = xx;
      }
      #pragma unroll
      for (int m = 1; m < 16; m <<= 1) { float o2 = __shfl_xor(mx, m); mx = o2 > mx ? o2 : mx; }
      float sum = 0.f;
      #pragma unroll
      for (int nf = 0; nf < 14; nf++) {
        int col = nf * 16 + lrow;
        float pv = (col < CNF) ? exp2f((tv[nf] - mx) * 1.44269504f) : 0.f;
        tv[nf] = pv; sum += pv;
      }
      #pragma unroll
      for (int m = 1; m < 16; m <<= 1) sum += __shfl_xor(sum, m);
      float inv = 1.f / sum;
      int prow = mi * 16 + lk * 4 + r;
      #pragma unroll
      for (int nf = 0; nf < 14; nf++) {
        int col = nf * 16 + lrow;
        Pw[prow * 232 + col] = f2b(tv[nf] * inv * ms[col]);
      }
    }
  __syncthreads();

  f32x4 oacc[2][4];
  #pragma unroll
  for (int mi = 0; mi < 2; mi++)
    #pragma unroll
    for (int ni = 0; ni < 4; ni++) oacc[mi][ni] = zf;
  #pragma unroll
  for (int kt = 0; kt < 7; kt++) {
    bf16x8 pa0 = *(const bf16x8*)&Pw[lrow * 232 + kt * 32 + lk * 8];
    bf16x8 pa1 = *(const bf16x8*)&Pw[(16 + lrow) * 232 + kt * 32 + lk * 8];
    #pragma unroll
    for (int ni = 0; ni < 4; ni++) {
      bf16x8 bv = *(const bf16x8*)&Vt[(ni * 16 + lrow) * 232 + kt * 32 + lk * 8];
      oacc[0][ni] = __builtin_amdgcn_mfma_f32_16x16x32_bf16(pa0, bv, oacc[0][ni], 0, 0, 0);
      oacc[1][ni] = __builtin_amdgcn_mfma_f32_16x16x32_bf16(pa1, bv, oacc[1][ni], 0, 0, 0);
    }
  }

  #pragma unroll
  for (int mi = 0; mi < 2; mi++)
    #pragma unroll
    for (int ni = 0; ni < 4; ni++)
      #pragma unroll
      for (int r = 0; r < 4; r++) {
        int q = q0 + mi * 16 + lk * 4 + r;
        int qo;
        if (q == 0) qo = 0;
        else if (q >= 1 + CP && q < CNF) qo = q - CP;
        else continue;
        int col = hh * 64 + ni * 16 + lrow;
        o[((size_t)(b * CNT + qo)) * CD + col] = f2b(oacc[mi][ni][r]);
      }
}

// ---------------- final LN + head -------------------------------------------------
__global__ __launch_bounds__(256) void head_kernel(
    const float* __restrict__ h, const float* __restrict__ g, const float* __restrict__ bb,
    const float* __restrict__ hw, const float* __restrict__ hb, float* __restrict__ out)
{
  __shared__ float xn[768];
  __shared__ float ws1[4], ws2[4];
  int b = blockIdx.x;
  const float* src = h + (size_t)(b * CNT) * CD;
  int tidx = threadIdx.x;
  int wave = tidx >> 6, lane = tidx & 63;
  float vv[3];
  float s = 0.f, sq = 0.f;
  #pragma unroll
  for (int j = 0; j < 3; j++) { float xv = src[tidx + 256 * j]; vv[j] = xv; s += xv; sq += xv * xv; }
  #pragma unroll
  for (int m = 1; m < 64; m <<= 1) { s += __shfl_xor(s, m); sq += __shfl_xor(sq, m); }
  if (lane == 0) { ws1[wave] = s; ws2[wave] = sq; }
  __syncthreads();
  s = ws1[0] + ws1[1] + ws1[2] + ws1[3];
  sq = ws2[0] + ws2[1] + ws2[2] + ws2[3];
  float mean = s * (1.f / 768.f);
  float var = sq * (1.f / 768.f) - mean * mean;
  float rs = rsqrtf(var + 1e-6f);
  #pragma unroll
  for (int j = 0; j < 3; j++) { int c = tidx + 256 * j; xn[c] = (vv[j] - mean) * rs * g[c] + bb[c]; }
  __syncthreads();
  if (tidx < CNCLS) {
    float acc = hb[tidx];
    for (int d = 0; d < 768; d++) acc += xn[d] * hw[d * CNCLS + tidx];
    out[b * CNCLS + tidx] = acc;
  }
}

// ---------------- host ------------------------------------------------------------
extern "C" void kernel_launch(void* const* d_in, const int* in_sizes, int n_in,
                              void* d_out, int out_size, void* d_ws, size_t ws_size,
                              hipStream_t stream)
{
  (void)in_sizes; (void)n_in; (void)out_size; (void)ws_size;
  const float* x       = (const float*)d_in[0];
  const float* patch_w = (const float*)d_in[1];
  const float* patch_b = (const float*)d_in[2];
  const float* cls_tok = (const float*)d_in[3];
  const float* pos     = (const float*)d_in[4];
  const float* prompts = (const float*)d_in[5];
  const float* masks   = (const float*)d_in[6];
  const float* advp_w  = (const float*)d_in[7];
  const float* advp_b  = (const float*)d_in[8];
  const float* ln1_g   = (const float*)d_in[9];
  const float* ln1_b   = (const float*)d_in[10];
  const float* qkv_w   = (const float*)d_in[11];
  const float* qkv_b   = (const float*)d_in[12];
  const float* proj_w  = (const float*)d_in[13];
  const float* proj_b  = (const float*)d_in[14];
  const float* ln2_g   = (const float*)d_in[15];
  const float* ln2_b   = (const float*)d_in[16];
  const float* fc1_w   = (const float*)d_in[17];
  const float* fc1_b   = (const float*)d_in[18];
  const float* fc2_w   = (const float*)d_in[19];
  const float* fc2_b   = (const float*)d_in[20];
  const float* norm_g  = (const float*)d_in[21];
  const float* norm_b  = (const float*)d_in[22];
  const float* head_w  = (const float*)d_in[23];
  const float* head_b  = (const float*)d_in[24];
  float* out = (float*)d_out;

  char* wsp = (char*)d_ws;
  auto alloc = [&](size_t bytes) -> void* {
    void* r = (void*)wsp; wsp += (bytes + 255) & ~(size_t)255; return r;
  };
  short* wq     = (short*)alloc((size_t)2304 * 768 * 2);
  short* wp     = (short*)alloc((size_t)768 * 768 * 2);
  short* w1     = (short*)alloc((size_t)3072 * 768 * 2);
  short* w2     = (short*)alloc((size_t)768 * 3072 * 2);
  short* wpatch = (short*)alloc((size_t)768 * 768 * 2);
  short* Pm     = (short*)alloc((size_t)12544 * 768 * 2);
  float* h      = (float*)alloc((size_t)12608 * 768 * 4);
  short* a_in   = (short*)alloc((size_t)13952 * 768 * 2);
  short* qkv    = (short*)alloc((size_t)13952 * 2304 * 2);
  short* ob     = (short*)alloc((size_t)12672 * 768 * 2);
  short* mb     = (short*)alloc((size_t)12672 * 768 * 2);
  short* g1     = (short*)alloc((size_t)12672 * 3072 * 2);
  float* Cc     = (float*)alloc((size_t)240 * 768 * 4);
  float* Ss     = (float*)alloc((size_t)240 * 768 * 4);
  float* pr     = (float*)alloc((size_t)240 * 768 * 4);

  fft_stage1<<<240, 256, 0, stream>>>(prompts, Cc, Ss);
  fft_stage2<<<240, 256, 0, stream>>>(Cc, Ss, pr);
  patch_build<<<37632, 256, 0, stream>>>(x, Pm);
  wtrans<<<dim3(24, 24), dim3(32, 8), 0, stream>>>(patch_w, wpatch, 768, 768);
  gemm_bt<3><<<dim3(98, 6), 256, 0, stream>>>(Pm, wpatch, patch_b, nullptr, h, pos, 12544, 768, 768);
  cls_pos<<<192, 256, 0, stream>>>(cls_tok, pos, h);

  for (int i = 0; i < CL; i++) {
    ln1_kernel<<<3472, 256, 0, stream>>>(h, pr + (size_t)i * 20 * 768, ln1_g + i * 768, ln1_b + i * 768, a_in);
    wtrans<<<dim3(24, 72), dim3(32, 8), 0, stream>>>(qkv_w + (size_t)i * 768 * 2304, wq, 768, 2304);
    gemm_bt<0><<<dim3(109, 18), 256, 0, stream>>>(a_in, wq, qkv_b + i * 2304, qkv, nullptr, nullptr, 13888, 2304, 768);
    attn_kernel<<<dim3(12, 64, 2), 256, 0, stream>>>(qkv, advp_w, advp_b, masks + i * CNF, ob);
    wtrans<<<dim3(24, 24), dim3(32, 8), 0, stream>>>(proj_w + (size_t)i * 768 * 768, wp, 768, 768);
    gemm_bt<2><<<dim3(99, 6), 256, 0, stream>>>(ob, wp, proj_b + i * 768, nullptr, h, nullptr, 12608, 768, 768);
    ln2_kernel<<<3152, 256, 0, stream>>>(h, ln2_g + i * 768, ln2_b + i * 768, mb);
    wtrans<<<dim3(24, 96), dim3(32, 8), 0, stream>>>(fc1_w + (size_t)i * 768 * 3072, w1, 768, 3072);
    gemm_bt<1><<<dim3(99, 24), 256, 0, stream>>>(mb, w1, fc1_b + i * 3072, g1, nullptr, nullptr, 12608, 3072, 768);
    wtrans<<<dim3(96, 24), dim3(32, 8), 0, stream>>>(fc2_w + (size_t)i * 3072 * 768, w2, 3072, 768);
    gemm_bt<2><<<dim3(99, 6), 256, 0, stream>>>(g1, w2, fc2_b + i * 768, nullptr, h, nullptr, 12608, 768, 3072);
  }
  head_kernel<<<64, 256, 0, stream>>>(h, norm_g, norm_b, head_w, head_b, out);
}

// Round 3
// 7014.878 us; speedup vs baseline: 1.0610x; 1.0610x over previous
//
#include <hip/hip_runtime.h>
#include <hip/hip_bf16.h>
#include <cstdint>

constexpr int CL = 12, CH = 12, CD = 768, CP = 20, CNT = 197, CNF = 217, CB = 64, CNCLS = 100;
constexpr float CSCALE = 0.125f;

typedef __bf16 bf16x8 __attribute__((ext_vector_type(8)));
typedef float f32x4 __attribute__((ext_vector_type(4)));
typedef short short4v __attribute__((ext_vector_type(4)));

__device__ __forceinline__ short f2b(float f){
  uint32_t x = __builtin_bit_cast(uint32_t, f);
  x = (x + 0x7fffu + ((x >> 16) & 1u)) >> 16;
  return (short)x;
}
__device__ __forceinline__ float b2f(short s){
  return __builtin_bit_cast(float, ((uint32_t)(uint16_t)s) << 16);
}
__device__ __forceinline__ unsigned pack2(float lo, float hi){
  return (unsigned)(uint16_t)f2b(lo) | ((unsigned)(uint16_t)f2b(hi) << 16);
}
__device__ __forceinline__ void gload_lds16(const short* g, short* l){
  __builtin_amdgcn_global_load_lds((const __attribute__((address_space(1))) void*)g,
                                   (__attribute__((address_space(3))) void*)l, 16, 0, 0);
}

// ---------------- GEMM: C[M,N] = A[M,K](bf16) * Bt[N,K]^T(bf16) + bias, epilogues ----
// EPI 0: bias -> bf16 store; 1: bias+gelu -> bf16; 2: bias + add into fp32 Cf; 3: patch (bias+pos -> Cf remapped rows)
template<int EPI>
__global__ __launch_bounds__(256, 2) void gemm_bt(
    const short* __restrict__ A, const short* __restrict__ Bt,
    const float* __restrict__ bias, short* __restrict__ Cb,
    float* __restrict__ Cf, const float* __restrict__ pos,
    int M, int N, int K)
{
  __shared__ short As[128 * 32];
  __shared__ short Bs[128 * 32];
  const int tid = threadIdx.x;
  const int wave = tid >> 6, lane = tid & 63;
  const int m0 = blockIdx.x * 128, n0 = blockIdx.y * 128;
  const int wr = wave >> 1, wc = wave & 1;
  const int lrow = lane & 15, lk = lane >> 4;

  f32x4 zf = {0.f, 0.f, 0.f, 0.f};
  f32x4 acc[4][4];
  #pragma unroll
  for (int i = 0; i < 4; i++)
    #pragma unroll
    for (int j = 0; j < 4; j++) acc[i][j] = zf;

  for (int k0 = 0; k0 < K; k0 += 32) {
    __syncthreads();
    #pragma unroll
    for (int i = 0; i < 2; i++) {
      int idx = i * 256 + tid;
      int row = idx >> 2, c8 = (idx & 3) * 8;
      int gra = m0 + row; gra = gra < M ? gra : M - 1;
      gload_lds16(A + (size_t)gra * K + k0 + c8, (short*)((char*)As + (i * 256 + wave * 64) * 16));
      int grb = n0 + row;
      gload_lds16(Bt + (size_t)grb * K + k0 + c8, (short*)((char*)Bs + (i * 256 + wave * 64) * 16));
    }
    __syncthreads();
    const short* pA = As + (wr * 64 + lrow) * 32 + lk * 8;
    const short* pB = Bs + (wc * 64 + lrow) * 32 + lk * 8;
    bf16x8 af[4], bfv[4];
    #pragma unroll
    for (int mi = 0; mi < 4; mi++) af[mi] = *(const bf16x8*)(pA + mi * 16 * 32);
    #pragma unroll
    for (int ni = 0; ni < 4; ni++) bfv[ni] = *(const bf16x8*)(pB + ni * 16 * 32);
    #pragma unroll
    for (int mi = 0; mi < 4; mi++)
      #pragma unroll
      for (int ni = 0; ni < 4; ni++)
        acc[mi][ni] = __builtin_amdgcn_mfma_f32_16x16x32_bf16(af[mi], bfv[ni], acc[mi][ni], 0, 0, 0);
  }

  #pragma unroll
  for (int mi = 0; mi < 4; mi++) {
    int rbase = m0 + wr * 64 + mi * 16 + lk * 4;
    #pragma unroll
    for (int ni = 0; ni < 4; ni++) {
      int col = n0 + wc * 64 + ni * 16 + lrow;
      float bv = bias[col];
      f32x4 v = acc[mi][ni];
      #pragma unroll
      for (int r = 0; r < 4; r++) {
        int row = rbase + r;
        if (row >= M) continue;
        float val = v[r] + bv;
        if constexpr (EPI == 0) {
          Cb[(size_t)row * N + col] = f2b(val);
        } else if constexpr (EPI == 1) {
          float g = 0.5f * val * (1.0f + erff(val * 0.70710678118f));
          Cb[(size_t)row * N + col] = f2b(g);
        } else if constexpr (EPI == 2) {
          Cf[(size_t)row * N + col] += val;
        } else {
          int b = row / 196, pp = row % 196;
          Cf[((size_t)(b * CNT + 1 + pp)) * CD + col] = val + pos[(1 + pp) * CD + col];
        }
      }
    }
  }
}

// ---------------- weight transpose + bf16 convert: in[K,N] f32 -> out[N,K] bf16 ------
__global__ void wtrans(const float* __restrict__ in, short* __restrict__ out, int K, int N)
{
  __shared__ float t[32][33];
  int tx = threadIdx.x, ty = threadIdx.y;
  int k0 = blockIdx.x * 32, n0 = blockIdx.y * 32;
  for (int i = ty; i < 32; i += 8)
    t[i][tx] = in[(size_t)(k0 + i) * N + n0 + tx];
  __syncthreads();
  for (int i = ty; i < 32; i += 8)
    out[(size_t)(n0 + i) * K + k0 + tx] = f2b(t[tx][i]);
}

// ---------------- patch matrix build: x[B,3,224,224] -> Pm[B*196, 768] bf16 ---------
__global__ void patch_build(const float* __restrict__ x, short* __restrict__ Pm)
{
  int idx = blockIdx.x * 256 + threadIdx.x;   // < 12544*768
  int r = idx / 768, c = idx % 768;
  int b = r / 196, np = r % 196;
  int gy = np / 14, gx = np % 14;
  int ch = c >> 8, rem = c & 255, py = rem >> 4, px = rem & 15;
  float v = x[((size_t)(b * 3 + ch) * 224 + gy * 16 + py) * 224 + gx * 16 + px];
  Pm[idx] = f2b(v);
}

__global__ void cls_pos(const float* __restrict__ cls, const float* __restrict__ pos, float* __restrict__ h)
{
  int idx = blockIdx.x * 256 + threadIdx.x;   // < 64*768
  int b = idx / 768, c = idx % 768;
  h[(size_t)(b * CNT) * CD + c] = cls[c] + pos[c];
}

// ---------------- FFT(prompts) real part, separable, all layers --------------------
__global__ __launch_bounds__(256) void fft_stage1(const float* __restrict__ prompts,
                                                  float* __restrict__ Cc, float* __restrict__ Ss)
{
  __shared__ float xr[768], ct[768], st[768];
  int blk = blockIdx.x;                       // layer*20 + p
  const float* src = prompts + (size_t)blk * 768;
  for (int c = threadIdx.x; c < 768; c += 256) {
    xr[c] = src[c];
    float ang = (float)c * (6.2831853071795864f / 768.f);
    float sv, cv; sincosf(ang, &sv, &cv);
    ct[c] = cv; st[c] = sv;
  }
  __syncthreads();
  for (int k = threadIdx.x; k < 768; k += 256) {
    float cs = 0.f, sn = 0.f; int idx = 0;
    for (int d = 0; d < 768; d++) {
      float xv = xr[d];
      cs += xv * ct[idx];
      sn += xv * st[idx];
      idx += k; if (idx >= 768) idx -= 768;
    }
    Cc[(size_t)blk * 768 + k] = cs;
    Ss[(size_t)blk * 768 + k] = sn;
  }
}

__global__ __launch_bounds__(256) void fft_stage2(const float* __restrict__ Cc, const float* __restrict__ Ss,
                                                  float* __restrict__ pr)
{
  int blk = blockIdx.x; int layer = blk / 20, q = blk % 20;
  __shared__ float tc[20], tsn[20];
  if (threadIdx.x < 20) {
    int j = threadIdx.x;
    float ang = (float)((q * j) % 20) * (6.2831853071795864f / 20.f);
    float sv, cv; sincosf(ang, &sv, &cv);
    tc[j] = cv; tsn[j] = sv;
  }
  __syncthreads();
  for (int k = threadIdx.x; k < 768; k += 256) {
    float acc = 0.f;
    #pragma unroll
    for (int p2 = 0; p2 < 20; p2++) {
      size_t off = ((size_t)(layer * 20 + p2)) * 768 + k;
      acc += Cc[off] * tc[p2] - Ss[off] * tsn[p2];
    }
    pr[((size_t)(layer * 20 + q)) * 768 + k] = acc;
  }
}

// ---------------- LayerNorms ------------------------------------------------------
__global__ __launch_bounds__(256) void ln1_kernel(
    const float* __restrict__ h, const float* __restrict__ pr,
    const float* __restrict__ g, const float* __restrict__ bb,
    short* __restrict__ outp)
{
  int wave = threadIdx.x >> 6, lane = threadIdx.x & 63;
  int row = blockIdx.x * 4 + wave;            // < 13888
  int b = row / CNF, t = row % CNF;
  const float* src;
  if (t == 0) src = h + (size_t)(b * CNT) * CD;
  else if (t <= CP) src = pr + (size_t)(t - 1) * CD;
  else src = h + (size_t)(b * CNT + (t - CP)) * CD;
  float4 v[3];
  float s = 0.f, sq = 0.f;
  #pragma unroll
  for (int j = 0; j < 3; j++) {
    v[j] = *(const float4*)(src + (lane + 64 * j) * 4);
    s += v[j].x + v[j].y + v[j].z + v[j].w;
    sq += v[j].x * v[j].x + v[j].y * v[j].y + v[j].z * v[j].z + v[j].w * v[j].w;
  }
  #pragma unroll
  for (int m = 1; m < 64; m <<= 1) { s += __shfl_xor(s, m); sq += __shfl_xor(sq, m); }
  float mean = s * (1.f / 768.f);
  float var = sq * (1.f / 768.f) - mean * mean;
  float rs = rsqrtf(var + 1e-6f);
  short* orow = outp + (size_t)row * CD;
  #pragma unroll
  for (int j = 0; j < 3; j++) {
    int c = (lane + 64 * j) * 4;
    float4 gg = *(const float4*)(g + c);
    float4 bv = *(const float4*)(bb + c);
    short4v o;
    o.x = f2b((v[j].x - mean) * rs * gg.x + bv.x);
    o.y = f2b((v[j].y - mean) * rs * gg.y + bv.y);
    o.z = f2b((v[j].z - mean) * rs * gg.z + bv.z);
    o.w = f2b((v[j].w - mean) * rs * gg.w + bv.w);
    *(short4v*)(orow + c) = o;
  }
}

__global__ __launch_bounds__(256) void ln2_kernel(
    const float* __restrict__ h, const float* __restrict__ g, const float* __restrict__ bb,
    short* __restrict__ outp)
{
  int wave = threadIdx.x >> 6, lane = threadIdx.x & 63;
  int row = blockIdx.x * 4 + wave;            // < 12608
  const float* src = h + (size_t)row * CD;
  float4 v[3];
  float s = 0.f, sq = 0.f;
  #pragma unroll
  for (int j = 0; j < 3; j++) {
    v[j] = *(const float4*)(src + (lane + 64 * j) * 4);
    s += v[j].x + v[j].y + v[j].z + v[j].w;
    sq += v[j].x * v[j].x + v[j].y * v[j].y + v[j].z * v[j].z + v[j].w * v[j].w;
  }
  #pragma unroll
  for (int m = 1; m < 64; m <<= 1) { s += __shfl_xor(s, m); sq += __shfl_xor(sq, m); }
  float mean = s * (1.f / 768.f);
  float var = sq * (1.f / 768.f) - mean * mean;
  float rs = rsqrtf(var + 1e-6f);
  short* orow = outp + (size_t)row * CD;
  #pragma unroll
  for (int j = 0; j < 3; j++) {
    int c = (lane + 64 * j) * 4;
    float4 gg = *(const float4*)(g + c);
    float4 bv = *(const float4*)(bb + c);
    short4v o;
    o.x = f2b((v[j].x - mean) * rs * gg.x + bv.x);
    o.y = f2b((v[j].y - mean) * rs * gg.y + bv.y);
    o.z = f2b((v[j].z - mean) * rs * gg.z + bv.z);
    o.w = f2b((v[j].w - mean) * rs * gg.w + bv.w);
    *(short4v*)(orow + c) = o;
  }
}

// ---------------- fused attention v2: swapped QK^T, in-register softmax/P ----------
// Grid (H, B); 4 waves; each wave handles q-tiles pi = wave, wave+4, ... (<14).
// S^T = mfma(A=K, B=Q): lane holds q = lrow (col), keys T = nf*16 + lk*4 + r (row).
// Softmax row-reduce over 4-lane group {lrow, lk=0..3} via shfl_xor 16/32.
// P A-fragments for PV built in-register: target (kt,lk,j): T = kt*32+lk*8+j ->
//   src lane = lrow + 16*(2*(lk&1) + (j>=4)), reg nf = 2kt+(lk>>1), r = j&3.
// Only V^T (ADVP applied) lives in LDS.
__global__ __launch_bounds__(256, 3) void attn_kernel(
    const short* __restrict__ qkv, const float* __restrict__ aw,
    const float* __restrict__ ab, const float* __restrict__ mask,
    short* __restrict__ o)
{
  __shared__ short Vt[64 * 232];       // V^T [d][token], row stride 232 shorts
  __shared__ float ms[224];
  const int hh = blockIdx.x, b = blockIdx.y;
  const int tid = threadIdx.x, wave = tid >> 6, lane = tid & 63;
  const int lrow = lane & 15, lk = lane >> 4;

  for (int t = tid; t < 224; t += 256) ms[t] = (t < CNF) ? mask[t] : 0.f;
  for (int idx = tid; idx < 224 * 8; idx += 256) {
    int t = idx >> 3, c8 = (idx & 7) * 8;
    short tmp[8];
    if (t < CNF) {
      *(uint4*)tmp = *(const uint4*)(qkv + ((size_t)(b * CNF + t)) * 2304 + 1536 + hh * 64 + c8);
      if (t >= 1 && t <= CP) {
        const float* awp = aw + (size_t)(t - 1) * CD + hh * 64 + c8;
        const float* abp = ab + (size_t)(t - 1) * CD + hh * 64 + c8;
        #pragma unroll
        for (int w = 0; w < 8; w++) tmp[w] = f2b(b2f(tmp[w]) * awp[w] + abp[w]);
      }
    } else {
      #pragma unroll
      for (int w = 0; w < 8; w++) tmp[w] = 0;
    }
    #pragma unroll
    for (int w = 0; w < 8; w++) Vt[(c8 + w) * 232 + t] = tmp[w];
  }
  __syncthreads();

  const short* qkbase = qkv + (size_t)b * CNF * 2304 + hh * 64;
  const f32x4 zf = {0.f, 0.f, 0.f, 0.f};

  for (int pi = wave; pi < 14; pi += 4) {
    // ---- QK^T (swapped): Q fragment as B-operand --------------------------------
    int q = pi * 16 + lrow; if (q > CNF - 1) q = CNF - 1;
    const short* qb = qkbase + (size_t)q * 2304;
    bf16x8 bq0 = *(const bf16x8*)(qb + lk * 8);
    bf16x8 bq1 = *(const bf16x8*)(qb + 32 + lk * 8);

    f32x4 p[14];
    #pragma unroll
    for (int nf = 0; nf < 14; nf++) {
      int key = nf * 16 + lrow; if (key > CNF - 1) key = CNF - 1;
      const short* kb = qkbase + (size_t)key * 2304 + 768;
      bf16x8 ak0 = *(const bf16x8*)(kb + lk * 8);
      bf16x8 ak1 = *(const bf16x8*)(kb + 32 + lk * 8);
      f32x4 acc = zf;
      acc = __builtin_amdgcn_mfma_f32_16x16x32_bf16(ak0, bq0, acc, 0, 0, 0);
      acc = __builtin_amdgcn_mfma_f32_16x16x32_bf16(ak1, bq1, acc, 0, 0, 0);
      p[nf] = acc;
    }

    // ---- softmax over keys (4-lane group reduce) --------------------------------
    float mx = -3.0e38f;
    #pragma unroll
    for (int nf = 0; nf < 14; nf++)
      #pragma unroll
      for (int r = 0; r < 4; r++) {
        int T = nf * 16 + lk * 4 + r;
        float v = p[nf][r] * CSCALE;
        v = (T < CNF) ? v : -3.0e38f;
        p[nf][r] = v;
        mx = fmaxf(mx, v);
      }
    mx = fmaxf(mx, __shfl_xor(mx, 16));
    mx = fmaxf(mx, __shfl_xor(mx, 32));
    float sum = 0.f;
    #pragma unroll
    for (int nf = 0; nf < 14; nf++)
      #pragma unroll
      for (int r = 0; r < 4; r++) {
        float e = exp2f((p[nf][r] - mx) * 1.44269504f);
        p[nf][r] = e; sum += e;
      }
    sum += __shfl_xor(sum, 16);
    sum += __shfl_xor(sum, 32);
    float inv = 1.f / sum;

    // ---- normalize * mask, pack to 2xbf16 words ---------------------------------
    unsigned W01[14], W23[14];
    #pragma unroll
    for (int nf = 0; nf < 14; nf++) {
      int T = nf * 16 + lk * 4;
      float p0 = p[nf][0] * inv * ms[T];
      float p1 = p[nf][1] * inv * ms[T + 1];
      float p2 = p[nf][2] * inv * ms[T + 2];
      float p3 = p[nf][3] * inv * ms[T + 3];
      W01[nf] = pack2(p0, p1);
      W23[nf] = pack2(p2, p3);
    }

    // ---- PV: shuffle P^T -> P A-fragments, MFMA against V^T from LDS ------------
    f32x4 oa[4];
    #pragma unroll
    for (int ni = 0; ni < 4; ni++) oa[ni] = zf;
    const int base = lrow + (lk & 1) * 32;
    const bool hi = lk >= 2;
    #pragma unroll
    for (int kt = 0; kt < 7; kt++) {
      unsigned wa, wb, w0, w1, w2, w3;
      wa = (unsigned)__shfl((int)W01[2 * kt], base);
      wb = (unsigned)__shfl((int)W01[2 * kt + 1], base);
      w0 = hi ? wb : wa;
      wa = (unsigned)__shfl((int)W23[2 * kt], base);
      wb = (unsigned)__shfl((int)W23[2 * kt + 1], base);
      w1 = hi ? wb : wa;
      wa = (unsigned)__shfl((int)W01[2 * kt], base + 16);
      wb = (unsigned)__shfl((int)W01[2 * kt + 1], base + 16);
      w2 = hi ? wb : wa;
      wa = (unsigned)__shfl((int)W23[2 * kt], base + 16);
      wb = (unsigned)__shfl((int)W23[2 * kt + 1], base + 16);
      w3 = hi ? wb : wa;
      uint4 wv; wv.x = w0; wv.y = w1; wv.z = w2; wv.w = w3;
      bf16x8 pa = __builtin_bit_cast(bf16x8, wv);
      #pragma unroll
      for (int ni = 0; ni < 4; ni++) {
        bf16x8 bv = *(const bf16x8*)&Vt[(ni * 16 + lrow) * 232 + kt * 32 + lk * 8];
        oa[ni] = __builtin_amdgcn_mfma_f32_16x16x32_bf16(pa, bv, oa[ni], 0, 0, 0);
      }
    }

    // ---- store (drop prompt query rows) -----------------------------------------
    #pragma unroll
    for (int ni = 0; ni < 4; ni++)
      #pragma unroll
      for (int r = 0; r < 4; r++) {
        int qq = pi * 16 + lk * 4 + r;
        int qo;
        if (qq == 0) qo = 0;
        else if (qq >= 1 + CP && qq < CNF) qo = qq - CP;
        else continue;
        o[((size_t)(b * CNT + qo)) * CD + hh * 64 + ni * 16 + lrow] = f2b(oa[ni][r]);
      }
  }
}

// ---------------- final LN + head -------------------------------------------------
__global__ __launch_bounds__(256) void head_kernel(
    const float* __restrict__ h, const float* __restrict__ g, const float* __restrict__ bb,
    const float* __restrict__ hw, const float* __restrict__ hb, float* __restrict__ out)
{
  __shared__ float xn[768];
  __shared__ float ws1[4], ws2[4];
  int b = blockIdx.x;
  const float* src = h + (size_t)(b * CNT) * CD;
  int tidx = threadIdx.x;
  int wave = tidx >> 6, lane = tidx & 63;
  float vv[3];
  float s = 0.f, sq = 0.f;
  #pragma unroll
  for (int j = 0; j < 3; j++) { float xv = src[tidx + 256 * j]; vv[j] = xv; s += xv; sq += xv * xv; }
  #pragma unroll
  for (int m = 1; m < 64; m <<= 1) { s += __shfl_xor(s, m); sq += __shfl_xor(sq, m); }
  if (lane == 0) { ws1[wave] = s; ws2[wave] = sq; }
  __syncthreads();
  s = ws1[0] + ws1[1] + ws1[2] + ws1[3];
  sq = ws2[0] + ws2[1] + ws2[2] + ws2[3];
  float mean = s * (1.f / 768.f);
  float var = sq * (1.f / 768.f) - mean * mean;
  float rs = rsqrtf(var + 1e-6f);
  #pragma unroll
  for (int j = 0; j < 3; j++) { int c = tidx + 256 * j; xn[c] = (vv[j] - mean) * rs * g[c] + bb[c]; }
  __syncthreads();
  if (tidx < CNCLS) {
    float acc = hb[tidx];
    for (int d = 0; d < 768; d++) acc += xn[d] * hw[d * CNCLS + tidx];
    out[b * CNCLS + tidx] = acc;
  }
}

// ---------------- host ------------------------------------------------------------
extern "C" void kernel_launch(void* const* d_in, const int* in_sizes, int n_in,
                              void* d_out, int out_size, void* d_ws, size_t ws_size,
                              hipStream_t stream)
{
  (void)in_sizes; (void)n_in; (void)out_size; (void)ws_size;
  const float* x       = (const float*)d_in[0];
  const float* patch_w = (const float*)d_in[1];
  const float* patch_b = (const float*)d_in[2];
  const float* cls_tok = (const float*)d_in[3];
  const float* pos     = (const float*)d_in[4];
  const float* prompts = (const float*)d_in[5];
  const float* masks   = (const float*)d_in[6];
  const float* advp_w  = (const float*)d_in[7];
  const float* advp_b  = (const float*)d_in[8];
  const float* ln1_g   = (const float*)d_in[9];
  const float* ln1_b   = (const float*)d_in[10];
  const float* qkv_w   = (const float*)d_in[11];
  const float* qkv_b   = (const float*)d_in[12];
  const float* proj_w  = (const float*)d_in[13];
  const float* proj_b  = (const float*)d_in[14];
  const float* ln2_g   = (const float*)d_in[15];
  const float* ln2_b   = (const float*)d_in[16];
  const float* fc1_w   = (const float*)d_in[17];
  const float* fc1_b   = (const float*)d_in[18];
  const float* fc2_w   = (const float*)d_in[19];
  const float* fc2_b   = (const float*)d_in[20];
  const float* norm_g  = (const float*)d_in[21];
  const float* norm_b  = (const float*)d_in[22];
  const float* head_w  = (const float*)d_in[23];
  const float* head_b  = (const float*)d_in[24];
  float* out = (float*)d_out;

  char* wsp = (char*)d_ws;
  auto alloc = [&](size_t bytes) -> void* {
    void* r = (void*)wsp; wsp += (bytes + 255) & ~(size_t)255; return r;
  };
  short* wq     = (short*)alloc((size_t)2304 * 768 * 2);
  short* wp     = (short*)alloc((size_t)768 * 768 * 2);
  short* w1     = (short*)alloc((size_t)3072 * 768 * 2);
  short* w2     = (short*)alloc((size_t)768 * 3072 * 2);
  short* wpatch = (short*)alloc((size_t)768 * 768 * 2);
  short* Pm     = (short*)alloc((size_t)12544 * 768 * 2);
  float* h      = (float*)alloc((size_t)12608 * 768 * 4);
  short* a_in   = (short*)alloc((size_t)13952 * 768 * 2);
  short* qkv    = (short*)alloc((size_t)13952 * 2304 * 2);
  short* ob     = (short*)alloc((size_t)12672 * 768 * 2);
  short* mb     = (short*)alloc((size_t)12672 * 768 * 2);
  short* g1     = (short*)alloc((size_t)12672 * 3072 * 2);
  float* Cc     = (float*)alloc((size_t)240 * 768 * 4);
  float* Ss     = (float*)alloc((size_t)240 * 768 * 4);
  float* pr     = (float*)alloc((size_t)240 * 768 * 4);

  fft_stage1<<<240, 256, 0, stream>>>(prompts, Cc, Ss);
  fft_stage2<<<240, 256, 0, stream>>>(Cc, Ss, pr);
  patch_build<<<37632, 256, 0, stream>>>(x, Pm);
  wtrans<<<dim3(24, 24), dim3(32, 8), 0, stream>>>(patch_w, wpatch, 768, 768);
  gemm_bt<3><<<dim3(98, 6), 256, 0, stream>>>(Pm, wpatch, patch_b, nullptr, h, pos, 12544, 768, 768);
  cls_pos<<<192, 256, 0, stream>>>(cls_tok, pos, h);

  for (int i = 0; i < CL; i++) {
    ln1_kernel<<<3472, 256, 0, stream>>>(h, pr + (size_t)i * 20 * 768, ln1_g + i * 768, ln1_b + i * 768, a_in);
    wtrans<<<dim3(24, 72), dim3(32, 8), 0, stream>>>(qkv_w + (size_t)i * 768 * 2304, wq, 768, 2304);
    gemm_bt<0><<<dim3(109, 18), 256, 0, stream>>>(a_in, wq, qkv_b + i * 2304, qkv, nullptr, nullptr, 13888, 2304, 768);
    attn_kernel<<<dim3(12, 64), 256, 0, stream>>>(qkv, advp_w, advp_b, masks + i * CNF, ob);
    wtrans<<<dim3(24, 24), dim3(32, 8), 0, stream>>>(proj_w + (size_t)i * 768 * 768, wp, 768, 768);
    gemm_bt<2><<<dim3(99, 6), 256, 0, stream>>>(ob, wp, proj_b + i * 768, nullptr, h, nullptr, 12608, 768, 768);
    ln2_kernel<<<3152, 256, 0, stream>>>(h, ln2_g + i * 768, ln2_b + i * 768, mb);
    wtrans<<<dim3(24, 96), dim3(32, 8), 0, stream>>>(fc1_w + (size_t)i * 768 * 3072, w1, 768, 3072);
    gemm_bt<1><<<dim3(99, 24), 256, 0, stream>>>(mb, w1, fc1_b + i * 3072, g1, nullptr, nullptr, 12608, 3072, 768);
    wtrans<<<dim3(96, 24), dim3(32, 8), 0, stream>>>(fc2_w + (size_t)i * 3072 * 768, w2, 3072, 768);
    gemm_bt<2><<<dim3(99, 6), 256, 0, stream>>>(g1, w2, fc2_b + i * 768, nullptr, h, nullptr, 12608, 768, 3072);
  }
  head_kernel<<<64, 256, 0, stream>>>(h, norm_g, norm_b, head_w, head_b, out);
}

// Round 5
// 6555.362 us; speedup vs baseline: 1.1354x; 1.0701x over previous
//
#include <hip/hip_runtime.h>
#include <hip/hip_bf16.h>
#include <cstdint>

constexpr int CL = 12, CH = 12, CD = 768, CP = 20, CNT = 197, CNF = 217, CB = 64, CNCLS = 100;
constexpr float CSCALE = 0.125f;

typedef __bf16 bf16x8 __attribute__((ext_vector_type(8)));
typedef float f32x4 __attribute__((ext_vector_type(4)));
typedef short short4v __attribute__((ext_vector_type(4)));

__device__ __forceinline__ short f2b(float f){
  uint32_t x = __builtin_bit_cast(uint32_t, f);
  x = (x + 0x7fffu + ((x >> 16) & 1u)) >> 16;
  return (short)x;
}
__device__ __forceinline__ float b2f(short s){
  return __builtin_bit_cast(float, ((uint32_t)(uint16_t)s) << 16);
}
__device__ __forceinline__ float b2fu(unsigned u){   // low 16 bits = bf16
  return __builtin_bit_cast(float, u << 16);
}
__device__ __forceinline__ unsigned pack2(float lo, float hi){
  return (unsigned)(uint16_t)f2b(lo) | ((unsigned)(uint16_t)f2b(hi) << 16);
}
__device__ __forceinline__ void gload_lds16(const short* g, short* l){
  __builtin_amdgcn_global_load_lds((const __attribute__((address_space(1))) void*)g,
                                   (__attribute__((address_space(3))) void*)l, 16, 0, 0);
}

// ---------------- GEMM: C[M,N] = A[M,K](bf16) * Bt[N,K]^T(bf16) + bias, epilogues ----
// EPI 0: bias -> bf16 store; 1: bias+gelu -> bf16; 2: bias + add into fp32 Cf; 3: patch (bias+pos -> Cf remapped rows)
template<int EPI>
__global__ __launch_bounds__(256, 2) void gemm_bt(
    const short* __restrict__ A, const short* __restrict__ Bt,
    const float* __restrict__ bias, short* __restrict__ Cb,
    float* __restrict__ Cf, const float* __restrict__ pos,
    int M, int N, int K)
{
  __shared__ short As[128 * 32];
  __shared__ short Bs[128 * 32];
  const int tid = threadIdx.x;
  const int wave = tid >> 6, lane = tid & 63;
  const int m0 = blockIdx.x * 128, n0 = blockIdx.y * 128;
  const int wr = wave >> 1, wc = wave & 1;
  const int lrow = lane & 15, lk = lane >> 4;

  f32x4 zf = {0.f, 0.f, 0.f, 0.f};
  f32x4 acc[4][4];
  #pragma unroll
  for (int i = 0; i < 4; i++)
    #pragma unroll
    for (int j = 0; j < 4; j++) acc[i][j] = zf;

  for (int k0 = 0; k0 < K; k0 += 32) {
    __syncthreads();
    #pragma unroll
    for (int i = 0; i < 2; i++) {
      int idx = i * 256 + tid;
      int row = idx >> 2, c8 = (idx & 3) * 8;
      int gra = m0 + row; gra = gra < M ? gra : M - 1;
      gload_lds16(A + (size_t)gra * K + k0 + c8, (short*)((char*)As + (i * 256 + wave * 64) * 16));
      int grb = n0 + row;
      gload_lds16(Bt + (size_t)grb * K + k0 + c8, (short*)((char*)Bs + (i * 256 + wave * 64) * 16));
    }
    __syncthreads();
    const short* pA = As + (wr * 64 + lrow) * 32 + lk * 8;
    const short* pB = Bs + (wc * 64 + lrow) * 32 + lk * 8;
    bf16x8 af[4], bfv[4];
    #pragma unroll
    for (int mi = 0; mi < 4; mi++) af[mi] = *(const bf16x8*)(pA + mi * 16 * 32);
    #pragma unroll
    for (int ni = 0; ni < 4; ni++) bfv[ni] = *(const bf16x8*)(pB + ni * 16 * 32);
    #pragma unroll
    for (int mi = 0; mi < 4; mi++)
      #pragma unroll
      for (int ni = 0; ni < 4; ni++)
        acc[mi][ni] = __builtin_amdgcn_mfma_f32_16x16x32_bf16(af[mi], bfv[ni], acc[mi][ni], 0, 0, 0);
  }

  #pragma unroll
  for (int mi = 0; mi < 4; mi++) {
    int rbase = m0 + wr * 64 + mi * 16 + lk * 4;
    #pragma unroll
    for (int ni = 0; ni < 4; ni++) {
      int col = n0 + wc * 64 + ni * 16 + lrow;
      float bv = bias[col];
      f32x4 v = acc[mi][ni];
      #pragma unroll
      for (int r = 0; r < 4; r++) {
        int row = rbase + r;
        if (row >= M) continue;
        float val = v[r] + bv;
        if constexpr (EPI == 0) {
          Cb[(size_t)row * N + col] = f2b(val);
        } else if constexpr (EPI == 1) {
          float g = 0.5f * val * (1.0f + erff(val * 0.70710678118f));
          Cb[(size_t)row * N + col] = f2b(g);
        } else if constexpr (EPI == 2) {
          Cf[(size_t)row * N + col] += val;
        } else {
          int b = row / 196, pp = row % 196;
          Cf[((size_t)(b * CNT + 1 + pp)) * CD + col] = val + pos[(1 + pp) * CD + col];
        }
      }
    }
  }
}

// ---------------- weight transpose + bf16 convert: in[K,N] f32 -> out[N,K] bf16 ------
__global__ void wtrans(const float* __restrict__ in, short* __restrict__ out, int K, int N)
{
  __shared__ float t[32][33];
  int tx = threadIdx.x, ty = threadIdx.y;
  int k0 = blockIdx.x * 32, n0 = blockIdx.y * 32;
  for (int i = ty; i < 32; i += 8)
    t[i][tx] = in[(size_t)(k0 + i) * N + n0 + tx];
  __syncthreads();
  for (int i = ty; i < 32; i += 8)
    out[(size_t)(n0 + i) * K + k0 + tx] = f2b(t[tx][i]);
}

// ---------------- patch matrix build: x[B,3,224,224] -> Pm[B*196, 768] bf16 ---------
__global__ void patch_build(const float* __restrict__ x, short* __restrict__ Pm)
{
  int idx = blockIdx.x * 256 + threadIdx.x;   // < 12544*768
  int r = idx / 768, c = idx % 768;
  int b = r / 196, np = r % 196;
  int gy = np / 14, gx = np % 14;
  int ch = c >> 8, rem = c & 255, py = rem >> 4, px = rem & 15;
  float v = x[((size_t)(b * 3 + ch) * 224 + gy * 16 + py) * 224 + gx * 16 + px];
  Pm[idx] = f2b(v);
}

__global__ void cls_pos(const float* __restrict__ cls, const float* __restrict__ pos, float* __restrict__ h)
{
  int idx = blockIdx.x * 256 + threadIdx.x;   // < 64*768
  int b = idx / 768, c = idx % 768;
  h[(size_t)(b * CNT) * CD + c] = cls[c] + pos[c];
}

// ---------------- FFT(prompts) real part, separable, all layers --------------------
__global__ __launch_bounds__(256) void fft_stage1(const float* __restrict__ prompts,
                                                  float* __restrict__ Cc, float* __restrict__ Ss)
{
  __shared__ float xr[768], ct[768], st[768];
  int blk = blockIdx.x;                       // layer*20 + p
  const float* src = prompts + (size_t)blk * 768;
  for (int c = threadIdx.x; c < 768; c += 256) {
    xr[c] = src[c];
    float ang = (float)c * (6.2831853071795864f / 768.f);
    float sv, cv; sincosf(ang, &sv, &cv);
    ct[c] = cv; st[c] = sv;
  }
  __syncthreads();
  for (int k = threadIdx.x; k < 768; k += 256) {
    float cs = 0.f, sn = 0.f; int idx = 0;
    for (int d = 0; d < 768; d++) {
      float xv = xr[d];
      cs += xv * ct[idx];
      sn += xv * st[idx];
      idx += k; if (idx >= 768) idx -= 768;
    }
    Cc[(size_t)blk * 768 + k] = cs;
    Ss[(size_t)blk * 768 + k] = sn;
  }
}

__global__ __launch_bounds__(256) void fft_stage2(const float* __restrict__ Cc, const float* __restrict__ Ss,
                                                  float* __restrict__ pr)
{
  int blk = blockIdx.x; int layer = blk / 20, q = blk % 20;
  __shared__ float tc[20], tsn[20];
  if (threadIdx.x < 20) {
    int j = threadIdx.x;
    float ang = (float)((q * j) % 20) * (6.2831853071795864f / 20.f);
    float sv, cv; sincosf(ang, &sv, &cv);
    tc[j] = cv; tsn[j] = sv;
  }
  __syncthreads();
  for (int k = threadIdx.x; k < 768; k += 256) {
    float acc = 0.f;
    #pragma unroll
    for (int p2 = 0; p2 < 20; p2++) {
      size_t off = ((size_t)(layer * 20 + p2)) * 768 + k;
      acc += Cc[off] * tc[p2] - Ss[off] * tsn[p2];
    }
    pr[((size_t)(layer * 20 + q)) * 768 + k] = acc;
  }
}

// ---------------- LayerNorms ------------------------------------------------------
__global__ __launch_bounds__(256) void ln1_kernel(
    const float* __restrict__ h, const float* __restrict__ pr,
    const float* __restrict__ g, const float* __restrict__ bb,
    short* __restrict__ outp)
{
  int wave = threadIdx.x >> 6, lane = threadIdx.x & 63;
  int row = blockIdx.x * 4 + wave;            // < 13888
  int b = row / CNF, t = row % CNF;
  const float* src;
  if (t == 0) src = h + (size_t)(b * CNT) * CD;
  else if (t <= CP) src = pr + (size_t)(t - 1) * CD;
  else src = h + (size_t)(b * CNT + (t - CP)) * CD;
  float4 v[3];
  float s = 0.f, sq = 0.f;
  #pragma unroll
  for (int j = 0; j < 3; j++) {
    v[j] = *(const float4*)(src + (lane + 64 * j) * 4);
    s += v[j].x + v[j].y + v[j].z + v[j].w;
    sq += v[j].x * v[j].x + v[j].y * v[j].y + v[j].z * v[j].z + v[j].w * v[j].w;
  }
  #pragma unroll
  for (int m = 1; m < 64; m <<= 1) { s += __shfl_xor(s, m); sq += __shfl_xor(sq, m); }
  float mean = s * (1.f / 768.f);
  float var = sq * (1.f / 768.f) - mean * mean;
  float rs = rsqrtf(var + 1e-6f);
  short* orow = outp + (size_t)row * CD;
  #pragma unroll
  for (int j = 0; j < 3; j++) {
    int c = (lane + 64 * j) * 4;
    float4 gg = *(const float4*)(g + c);
    float4 bv = *(const float4*)(bb + c);
    short4v o;
    o.x = f2b((v[j].x - mean) * rs * gg.x + bv.x);
    o.y = f2b((v[j].y - mean) * rs * gg.y + bv.y);
    o.z = f2b((v[j].z - mean) * rs * gg.z + bv.z);
    o.w = f2b((v[j].w - mean) * rs * gg.w + bv.w);
    *(short4v*)(orow + c) = o;
  }
}

__global__ __launch_bounds__(256) void ln2_kernel(
    const float* __restrict__ h, const float* __restrict__ g, const float* __restrict__ bb,
    short* __restrict__ outp)
{
  int wave = threadIdx.x >> 6, lane = threadIdx.x & 63;
  int row = blockIdx.x * 4 + wave;            // < 12608
  const float* src = h + (size_t)row * CD;
  float4 v[3];
  float s = 0.f, sq = 0.f;
  #pragma unroll
  for (int j = 0; j < 3; j++) {
    v[j] = *(const float4*)(src + (lane + 64 * j) * 4);
    s += v[j].x + v[j].y + v[j].z + v[j].w;
    sq += v[j].x * v[j].x + v[j].y * v[j].y + v[j].z * v[j].z + v[j].w * v[j].w;
  }
  #pragma unroll
  for (int m = 1; m < 64; m <<= 1) { s += __shfl_xor(s, m); sq += __shfl_xor(sq, m); }
  float mean = s * (1.f / 768.f);
  float var = sq * (1.f / 768.f) - mean * mean;
  float rs = rsqrtf(var + 1e-6f);
  short* orow = outp + (size_t)row * CD;
  #pragma unroll
  for (int j = 0; j < 3; j++) {
    int c = (lane + 64 * j) * 4;
    float4 gg = *(const float4*)(g + c);
    float4 bv = *(const float4*)(bb + c);
    short4v o;
    o.x = f2b((v[j].x - mean) * rs * gg.x + bv.x);
    o.y = f2b((v[j].y - mean) * rs * gg.y + bv.y);
    o.z = f2b((v[j].z - mean) * rs * gg.z + bv.z);
    o.w = f2b((v[j].w - mean) * rs * gg.w + bv.w);
    *(short4v*)(orow + c) = o;
  }
}

// ---------------- fused attention v3b: K in LDS (swizzled via gload_lds src-permute),
// V^T in LDS (swizzled, scratch-free staging), swapped QK^T, in-register softmax/P.
// Swizzle: byte ^= f(row)<<4 with f(r) = (r ^ (r>>3)) & 7; K stride 128 B, Vt stride 512 B.
// v3 bug fixed: write-side swizzle must use the FULL dest row (it*32+t), not t.
__global__ __launch_bounds__(256, 2) void attn_kernel(
    const short* __restrict__ qkv, const float* __restrict__ aw,
    const float* __restrict__ ab, const float* __restrict__ mask,
    short* __restrict__ o)
{
  __shared__ short Ks[224 * 64];       // [key][d], row 128 B, chunk-swizzled
  __shared__ short Vt[64 * 256];       // [d][token], row 512 B, chunk-swizzled
  __shared__ float ms[224];
  const int hh = blockIdx.x, b = blockIdx.y;
  const int tid = threadIdx.x, wave = tid >> 6, lane = tid & 63;
  const int lrow = lane & 15, lk = lane >> 4;
  char* const Ks_c = (char*)Ks;
  char* const Vt_c = (char*)Vt;

  for (int t = tid; t < 224; t += 256) ms[t] = (t < CNF) ? mask[t] : 0.f;

  // ---- K staging: global_load_lds, linear dest, source chunk pre-swizzled ------
  {
    const int t = tid >> 3;                        // row within 32-row chunk
    #pragma unroll
    for (int it = 0; it < 7; it++) {
      int row = it * 32 + t;                       // true dest row
      int f = (row ^ (row >> 3)) & 7;
      int rc = row < CNF ? row : CNF - 1;          // clamp (rows >=217 masked later)
      const short* src = qkv + ((size_t)(b * CNF + rc)) * 2304 + 768 + hh * 64 + (((tid & 7) ^ f) << 3);
      gload_lds16(src, (short*)(Ks_c + (it * 256 + wave * 64) * 16));
    }
  }

  // ---- V staging: reg-only (no arrays), scalar swizzled ds_write ---------------
  for (int idx = tid; idx < 224 * 8; idx += 256) {
    int t = idx >> 3, c8 = (idx & 7) * 8;
    unsigned w0 = 0, w1 = 0, w2 = 0, w3 = 0;
    if (t < CNF) {
      uint4 val = *(const uint4*)(qkv + ((size_t)(b * CNF + t)) * 2304 + 1536 + hh * 64 + c8);
      w0 = val.x; w1 = val.y; w2 = val.z; w3 = val.w;
    }
    float f0 = b2fu(w0 & 0xffffu), f1 = b2fu(w0 >> 16);
    float f2 = b2fu(w1 & 0xffffu), f3 = b2fu(w1 >> 16);
    float f4 = b2fu(w2 & 0xffffu), f5 = b2fu(w2 >> 16);
    float f6 = b2fu(w3 & 0xffffu), f7 = b2fu(w3 >> 16);
    if (t >= 1 && t <= CP) {
      const float* awp = aw + (size_t)(t - 1) * CD + hh * 64 + c8;
      const float* abp = ab + (size_t)(t - 1) * CD + hh * 64 + c8;
      float4 a0 = *(const float4*)awp, a1 = *(const float4*)(awp + 4);
      float4 b0 = *(const float4*)abp, b1 = *(const float4*)(abp + 4);
      f0 = f0 * a0.x + b0.x; f1 = f1 * a0.y + b0.y;
      f2 = f2 * a0.z + b0.z; f3 = f3 * a0.w + b0.w;
      f4 = f4 * a1.x + b1.x; f5 = f5 * a1.y + b1.y;
      f6 = f6 * a1.z + b1.z; f7 = f7 * a1.w + b1.w;
    }
    const int tb = 2 * t;
    const int d0 = c8;
    #pragma unroll
    for (int w = 0; w < 8; w++) {
      int d = d0 + w;
      int fsw = ((d ^ (d >> 3)) & 7) << 4;
      float fv = (w == 0) ? f0 : (w == 1) ? f1 : (w == 2) ? f2 : (w == 3) ? f3
               : (w == 4) ? f4 : (w == 5) ? f5 : (w == 6) ? f6 : f7;
      *(short*)(Vt_c + ((d * 512 + tb) ^ fsw)) = f2b(fv);
    }
  }
  __syncthreads();

  const short* qkbase = qkv + (size_t)b * CNF * 2304 + hh * 64;
  const f32x4 zf = {0.f, 0.f, 0.f, 0.f};

  for (int pi = wave; pi < 14; pi += 4) {
    // ---- QK^T (swapped): K rows from LDS (A-operand), Q from global (B) ---------
    int q = pi * 16 + lrow; if (q > CNF - 1) q = CNF - 1;
    const short* qb = qkbase + (size_t)q * 2304;
    bf16x8 bq0 = *(const bf16x8*)(qb + lk * 8);
    bf16x8 bq1 = *(const bf16x8*)(qb + 32 + lk * 8);

    f32x4 p[14];
    #pragma unroll
    for (int nf = 0; nf < 14; nf++) {
      int key = nf * 16 + lrow;
      int fk = (key ^ (key >> 3)) & 7;
      const char* kb = Ks_c + key * 128;
      bf16x8 ak0 = *(const bf16x8*)(kb + ((lk ^ fk) << 4));
      bf16x8 ak1 = *(const bf16x8*)(kb + (((4 + lk) ^ fk) << 4));
      f32x4 acc = zf;
      acc = __builtin_amdgcn_mfma_f32_16x16x32_bf16(ak0, bq0, acc, 0, 0, 0);
      acc = __builtin_amdgcn_mfma_f32_16x16x32_bf16(ak1, bq1, acc, 0, 0, 0);
      p[nf] = acc;
    }

    // ---- softmax over keys (4-lane group reduce) --------------------------------
    float mx = -3.0e38f;
    #pragma unroll
    for (int nf = 0; nf < 14; nf++)
      #pragma unroll
      for (int r = 0; r < 4; r++) {
        int T = nf * 16 + lk * 4 + r;
        float v = p[nf][r] * CSCALE;
        v = (T < CNF) ? v : -3.0e38f;
        p[nf][r] = v;
        mx = fmaxf(mx, v);
      }
    mx = fmaxf(mx, __shfl_xor(mx, 16));
    mx = fmaxf(mx, __shfl_xor(mx, 32));
    float sum = 0.f;
    #pragma unroll
    for (int nf = 0; nf < 14; nf++)
      #pragma unroll
      for (int r = 0; r < 4; r++) {
        float e = exp2f((p[nf][r] - mx) * 1.44269504f);
        p[nf][r] = e; sum += e;
      }
    sum += __shfl_xor(sum, 16);
    sum += __shfl_xor(sum, 32);
    float inv = 1.f / sum;

    // ---- normalize * mask, pack to 2xbf16 words ---------------------------------
    unsigned W01[14], W23[14];
    #pragma unroll
    for (int nf = 0; nf < 14; nf++) {
      int T = nf * 16 + lk * 4;
      float p0 = p[nf][0] * inv * ms[T];
      float p1 = p[nf][1] * inv * ms[T + 1];
      float p2 = p[nf][2] * inv * ms[T + 2];
      float p3 = p[nf][3] * inv * ms[T + 3];
      W01[nf] = pack2(p0, p1);
      W23[nf] = pack2(p2, p3);
    }

    // ---- PV: shuffle P^T -> P A-fragments, MFMA against V^T from LDS ------------
    f32x4 oa[4];
    #pragma unroll
    for (int ni = 0; ni < 4; ni++) oa[ni] = zf;
    const int base = lrow + (lk & 1) * 32;
    const bool hi = lk >= 2;
    #pragma unroll
    for (int kt = 0; kt < 7; kt++) {
      unsigned wa, wb, w0, w1, w2, w3;
      wa = (unsigned)__shfl((int)W01[2 * kt], base);
      wb = (unsigned)__shfl((int)W01[2 * kt + 1], base);
      w0 = hi ? wb : wa;
      wa = (unsigned)__shfl((int)W23[2 * kt], base);
      wb = (unsigned)__shfl((int)W23[2 * kt + 1], base);
      w1 = hi ? wb : wa;
      wa = (unsigned)__shfl((int)W01[2 * kt], base + 16);
      wb = (unsigned)__shfl((int)W01[2 * kt + 1], base + 16);
      w2 = hi ? wb : wa;
      wa = (unsigned)__shfl((int)W23[2 * kt], base + 16);
      wb = (unsigned)__shfl((int)W23[2 * kt + 1], base + 16);
      w3 = hi ? wb : wa;
      uint4 wv; wv.x = w0; wv.y = w1; wv.z = w2; wv.w = w3;
      bf16x8 pa = __builtin_bit_cast(bf16x8, wv);
      #pragma unroll
      for (int ni = 0; ni < 4; ni++) {
        int d = ni * 16 + lrow;
        int fv = ((d ^ (d >> 3)) & 7) << 4;
        bf16x8 bv = *(const bf16x8*)(Vt_c + ((d * 512 + ((kt * 4 + lk) << 4)) ^ fv));
        oa[ni] = __builtin_amdgcn_mfma_f32_16x16x32_bf16(pa, bv, oa[ni], 0, 0, 0);
      }
    }

    // ---- store (drop prompt query rows) -----------------------------------------
    #pragma unroll
    for (int ni = 0; ni < 4; ni++)
      #pragma unroll
      for (int r = 0; r < 4; r++) {
        int qq = pi * 16 + lk * 4 + r;
        int qo;
        if (qq == 0) qo = 0;
        else if (qq >= 1 + CP && qq < CNF) qo = qq - CP;
        else continue;
        o[((size_t)(b * CNT + qo)) * CD + hh * 64 + ni * 16 + lrow] = f2b(oa[ni][r]);
      }
  }
}

// ---------------- final LN + head -------------------------------------------------
__global__ __launch_bounds__(256) void head_kernel(
    const float* __restrict__ h, const float* __restrict__ g, const float* __restrict__ bb,
    const float* __restrict__ hw, const float* __restrict__ hb, float* __restrict__ out)
{
  __shared__ float xn[768];
  __shared__ float ws1[4], ws2[4];
  int b = blockIdx.x;
  const float* src = h + (size_t)(b * CNT) * CD;
  int tidx = threadIdx.x;
  int wave = tidx >> 6, lane = tidx & 63;
  float vv[3];
  float s = 0.f, sq = 0.f;
  #pragma unroll
  for (int j = 0; j < 3; j++) { float xv = src[tidx + 256 * j]; vv[j] = xv; s += xv; sq += xv * xv; }
  #pragma unroll
  for (int m = 1; m < 64; m <<= 1) { s += __shfl_xor(s, m); sq += __shfl_xor(sq, m); }
  if (lane == 0) { ws1[wave] = s; ws2[wave] = sq; }
  __syncthreads();
  s = ws1[0] + ws1[1] + ws1[2] + ws1[3];
  sq = ws2[0] + ws2[1] + ws2[2] + ws2[3];
  float mean = s * (1.f / 768.f);
  float var = sq * (1.f / 768.f) - mean * mean;
  float rs = rsqrtf(var + 1e-6f);
  #pragma unroll
  for (int j = 0; j < 3; j++) { int c = tidx + 256 * j; xn[c] = (vv[j] - mean) * rs * g[c] + bb[c]; }
  __syncthreads();
  if (tidx < CNCLS) {
    float acc = hb[tidx];
    for (int d = 0; d < 768; d++) acc += xn[d] * hw[d * CNCLS + tidx];
    out[b * CNCLS + tidx] = acc;
  }
}

// ---------------- host ------------------------------------------------------------
extern "C" void kernel_launch(void* const* d_in, const int* in_sizes, int n_in,
                              void* d_out, int out_size, void* d_ws, size_t ws_size,
                              hipStream_t stream)
{
  (void)in_sizes; (void)n_in; (void)out_size; (void)ws_size;
  const float* x       = (const float*)d_in[0];
  const float* patch_w = (const float*)d_in[1];
  const float* patch_b = (const float*)d_in[2];
  const float* cls_tok = (const float*)d_in[3];
  const float* pos     = (const float*)d_in[4];
  const float* prompts = (const float*)d_in[5];
  const float* masks   = (const float*)d_in[6];
  const float* advp_w  = (const float*)d_in[7];
  const float* advp_b  = (const float*)d_in[8];
  const float* ln1_g   = (const float*)d_in[9];
  const float* ln1_b   = (const float*)d_in[10];
  const float* qkv_w   = (const float*)d_in[11];
  const float* qkv_b   = (const float*)d_in[12];
  const float* proj_w  = (const float*)d_in[13];
  const float* proj_b  = (const float*)d_in[14];
  const float* ln2_g   = (const float*)d_in[15];
  const float* ln2_b   = (const float*)d_in[16];
  const float* fc1_w   = (const float*)d_in[17];
  const float* fc1_b   = (const float*)d_in[18];
  const float* fc2_w   = (const float*)d_in[19];
  const float* fc2_b   = (const float*)d_in[20];
  const float* norm_g  = (const float*)d_in[21];
  const float* norm_b  = (const float*)d_in[22];
  const float* head_w  = (const float*)d_in[23];
  const float* head_b  = (const float*)d_in[24];
  float* out = (float*)d_out;

  char* wsp = (char*)d_ws;
  auto alloc = [&](size_t bytes) -> void* {
    void* r = (void*)wsp; wsp += (bytes + 255) & ~(size_t)255; return r;
  };
  short* wq     = (short*)alloc((size_t)2304 * 768 * 2);
  short* wp     = (short*)alloc((size_t)768 * 768 * 2);
  short* w1     = (short*)alloc((size_t)3072 * 768 * 2);
  short* w2     = (short*)alloc((size_t)768 * 3072 * 2);
  short* wpatch = (short*)alloc((size_t)768 * 768 * 2);
  short* Pm     = (short*)alloc((size_t)12544 * 768 * 2);
  float* h      = (float*)alloc((size_t)12608 * 768 * 4);
  short* a_in   = (short*)alloc((size_t)13952 * 768 * 2);
  short* qkv    = (short*)alloc((size_t)13952 * 2304 * 2);
  short* ob     = (short*)alloc((size_t)12672 * 768 * 2);
  short* mb     = (short*)alloc((size_t)12672 * 768 * 2);
  short* g1     = (short*)alloc((size_t)12672 * 3072 * 2);
  float* Cc     = (float*)alloc((size_t)240 * 768 * 4);
  float* Ss     = (float*)alloc((size_t)240 * 768 * 4);
  float* pr     = (float*)alloc((size_t)240 * 768 * 4);

  fft_stage1<<<240, 256, 0, stream>>>(prompts, Cc, Ss);
  fft_stage2<<<240, 256, 0, stream>>>(Cc, Ss, pr);
  patch_build<<<37632, 256, 0, stream>>>(x, Pm);
  wtrans<<<dim3(24, 24), dim3(32, 8), 0, stream>>>(patch_w, wpatch, 768, 768);
  gemm_bt<3><<<dim3(98, 6), 256, 0, stream>>>(Pm, wpatch, patch_b, nullptr, h, pos, 12544, 768, 768);
  cls_pos<<<192, 256, 0, stream>>>(cls_tok, pos, h);

  for (int i = 0; i < CL; i++) {
    ln1_kernel<<<3472, 256, 0, stream>>>(h, pr + (size_t)i * 20 * 768, ln1_g + i * 768, ln1_b + i * 768, a_in);
    wtrans<<<dim3(24, 72), dim3(32, 8), 0, stream>>>(qkv_w + (size_t)i * 768 * 2304, wq, 768, 2304);
    gemm_bt<0><<<dim3(109, 18), 256, 0, stream>>>(a_in, wq, qkv_b + i * 2304, qkv, nullptr, nullptr, 13888, 2304, 768);
    attn_kernel<<<dim3(12, 64), 256, 0, stream>>>(qkv, advp_w, advp_b, masks + i * CNF, ob);
    wtrans<<<dim3(24, 24), dim3(32, 8), 0, stream>>>(proj_w + (size_t)i * 768 * 768, wp, 768, 768);
    gemm_bt<2><<<dim3(99, 6), 256, 0, stream>>>(ob, wp, proj_b + i * 768, nullptr, h, nullptr, 12608, 768, 768);
    ln2_kernel<<<3152, 256, 0, stream>>>(h, ln2_g + i * 768, ln2_b + i * 768, mb);
    wtrans<<<dim3(24, 96), dim3(32, 8), 0, stream>>>(fc1_w + (size_t)i * 768 * 3072, w1, 768, 3072);
    gemm_bt<1><<<dim3(99, 24), 256, 0, stream>>>(mb, w1, fc1_b + i * 3072, g1, nullptr, nullptr, 12608, 3072, 768);
    wtrans<<<dim3(96, 24), dim3(32, 8), 0, stream>>>(fc2_w + (size_t)i * 3072 * 768, w2, 3072, 768);
    gemm_bt<2><<<dim3(99, 6), 256, 0, stream>>>(g1, w2, fc2_b + i * 768, nullptr, h, nullptr, 12608, 768, 3072);
  }
  head_kernel<<<64, 256, 0, stream>>>(h, norm_g, norm_b, head_w, head_b, out);
}

// Round 6
// 5876.416 us; speedup vs baseline: 1.2666x; 1.1155x over previous
//
#include <hip/hip_runtime.h>
#include <hip/hip_bf16.h>
#include <cstdint>

constexpr int CL = 12, CH = 12, CD = 768, CP = 20, CNT = 197, CNF = 217, CB = 64, CNCLS = 100;
constexpr float CSCALE = 0.125f;

typedef __bf16 bf16x8 __attribute__((ext_vector_type(8)));
typedef float f32x4 __attribute__((ext_vector_type(4)));
typedef short short4v __attribute__((ext_vector_type(4)));

__device__ __forceinline__ short f2b(float f){
  uint32_t x = __builtin_bit_cast(uint32_t, f);
  x = (x + 0x7fffu + ((x >> 16) & 1u)) >> 16;
  return (short)x;
}
__device__ __forceinline__ float b2f(short s){
  return __builtin_bit_cast(float, ((uint32_t)(uint16_t)s) << 16);
}
__device__ __forceinline__ float b2fu(unsigned u){   // low 16 bits = bf16
  return __builtin_bit_cast(float, u << 16);
}
__device__ __forceinline__ unsigned pack2(float lo, float hi){
  return (unsigned)(uint16_t)f2b(lo) | ((unsigned)(uint16_t)f2b(hi) << 16);
}
__device__ __forceinline__ void gload_lds16(const short* g, short* l){
  __builtin_amdgcn_global_load_lds((const __attribute__((address_space(1))) void*)g,
                                   (__attribute__((address_space(3))) void*)l, 16, 0, 0);
}

// ---------------- GEMM v2: 2-phase pipelined, L2-chunked, XCD-swizzled --------------
// C[M,N] = A[M,K](bf16) * Bt[N,K]^T(bf16) + bias. 1-D grid = nch*MCH*(N/128).
// EPI 0: bias -> bf16; 1: bias+gelu -> bf16; 2: bias + add into fp32 Cf; 3: patch remap
template<int EPI>
__global__ __launch_bounds__(256, 2) void gemm_bt(
    const short* __restrict__ A, const short* __restrict__ Bt,
    const float* __restrict__ bias, short* __restrict__ Cb,
    float* __restrict__ Cf, const float* __restrict__ pos,
    int M, int N, int K, int MCH)
{
  __shared__ short As[2][128 * 32];
  __shared__ short Bs[2][128 * 32];
  const int tid = threadIdx.x;
  const int wave = tid >> 6, lane = tid & 63;
  const int wr = wave >> 1, wc = wave & 1;
  const int lrow = lane & 15, lk = lane >> 4;

  // --- bijective XCD swizzle (m204) + chunked decomposition (inner-M fastest) ----
  const int nwg = gridDim.x;
  const int orig = blockIdx.x;
  const int q = nwg >> 3, r = nwg & 7;
  const int xcd = orig & 7, lid = orig >> 3;
  const int flat = (xcd < r ? xcd * (q + 1) : r * (q + 1) + (xcd - r) * q) + lid;
  const int nn = N >> 7;
  const int per = MCH * nn;
  const int c0 = flat / per, rem = flat - c0 * per;
  const int n  = rem / MCH, im = rem - (rem / MCH) * MCH;
  const int mp = c0 * MCH + im;
  const int m0 = mp << 7, n0 = n << 7;
  if (m0 >= M) return;

  f32x4 zf = {0.f, 0.f, 0.f, 0.f};
  f32x4 acc[4][4];
  #pragma unroll
  for (int i = 0; i < 4; i++)
    #pragma unroll
    for (int j = 0; j < 4; j++) acc[i][j] = zf;

  auto STAGE = [&](int buf, int k0) {
    #pragma unroll
    for (int i = 0; i < 2; i++) {
      int idx = i * 256 + tid;
      int row = idx >> 2, c8 = (idx & 3) * 8;
      int gra = m0 + row; gra = gra < M ? gra : M - 1;
      gload_lds16(A + (size_t)gra * K + k0 + c8,
                  (short*)((char*)As + buf * 8192 + (i * 256 + wave * 64) * 16));
      int grb = n0 + row;
      gload_lds16(Bt + (size_t)grb * K + k0 + c8,
                  (short*)((char*)Bs + buf * 8192 + (i * 256 + wave * 64) * 16));
    }
  };

  STAGE(0, 0);
  __syncthreads();
  const int nt = K >> 5;
  for (int t = 0; t < nt; t++) {
    const int cur = t & 1;
    if (t + 1 < nt) STAGE(cur ^ 1, (t + 1) << 5);
    const short* pA = As[cur] + (wr * 64 + lrow) * 32 + lk * 8;
    const short* pB = Bs[cur] + (wc * 64 + lrow) * 32 + lk * 8;
    bf16x8 af[4], bfv[4];
    #pragma unroll
    for (int mi = 0; mi < 4; mi++) af[mi] = *(const bf16x8*)(pA + mi * 16 * 32);
    #pragma unroll
    for (int ni = 0; ni < 4; ni++) bfv[ni] = *(const bf16x8*)(pB + ni * 16 * 32);
    #pragma unroll
    for (int mi = 0; mi < 4; mi++)
      #pragma unroll
      for (int ni = 0; ni < 4; ni++)
        acc[mi][ni] = __builtin_amdgcn_mfma_f32_16x16x32_bf16(af[mi], bfv[ni], acc[mi][ni], 0, 0, 0);
    __syncthreads();
  }

  #pragma unroll
  for (int mi = 0; mi < 4; mi++) {
    int rbase = m0 + wr * 64 + mi * 16 + lk * 4;
    #pragma unroll
    for (int ni = 0; ni < 4; ni++) {
      int col = n0 + wc * 64 + ni * 16 + lrow;
      float bv = bias[col];
      f32x4 v = acc[mi][ni];
      #pragma unroll
      for (int r2 = 0; r2 < 4; r2++) {
        int row = rbase + r2;
        if (row >= M) continue;
        float val = v[r2] + bv;
        if constexpr (EPI == 0) {
          Cb[(size_t)row * N + col] = f2b(val);
        } else if constexpr (EPI == 1) {
          float g = 0.5f * val * (1.0f + erff(val * 0.70710678118f));
          Cb[(size_t)row * N + col] = f2b(g);
        } else if constexpr (EPI == 2) {
          Cf[(size_t)row * N + col] += val;
        } else {
          int b = row / 196, pp = row % 196;
          Cf[((size_t)(b * CNT + 1 + pp)) * CD + col] = val + pos[(1 + pp) * CD + col];
        }
      }
    }
  }
}

// ---------------- weight transpose + bf16 convert: in[K,N] f32 -> out[N,K] bf16 ------
__global__ void wtrans(const float* __restrict__ in, short* __restrict__ out, int K, int N)
{
  __shared__ float t[32][33];
  int tx = threadIdx.x, ty = threadIdx.y;
  int k0 = blockIdx.x * 32, n0 = blockIdx.y * 32;
  for (int i = ty; i < 32; i += 8)
    t[i][tx] = in[(size_t)(k0 + i) * N + n0 + tx];
  __syncthreads();
  for (int i = ty; i < 32; i += 8)
    out[(size_t)(n0 + i) * K + k0 + tx] = f2b(t[tx][i]);
}

// ---------------- patch matrix build: x[B,3,224,224] -> Pm[B*196, 768] bf16 ---------
__global__ void patch_build(const float* __restrict__ x, short* __restrict__ Pm)
{
  int idx = blockIdx.x * 256 + threadIdx.x;   // < 12544*768
  int r = idx / 768, c = idx % 768;
  int b = r / 196, np = r % 196;
  int gy = np / 14, gx = np % 14;
  int ch = c >> 8, rem = c & 255, py = rem >> 4, px = rem & 15;
  float v = x[((size_t)(b * 3 + ch) * 224 + gy * 16 + py) * 224 + gx * 16 + px];
  Pm[idx] = f2b(v);
}

__global__ void cls_pos(const float* __restrict__ cls, const float* __restrict__ pos, float* __restrict__ h)
{
  int idx = blockIdx.x * 256 + threadIdx.x;   // < 64*768
  int b = idx / 768, c = idx % 768;
  h[(size_t)(b * CNT) * CD + c] = cls[c] + pos[c];
}

// ---------------- FFT(prompts) real part, separable, all layers --------------------
__global__ __launch_bounds__(256) void fft_stage1(const float* __restrict__ prompts,
                                                  float* __restrict__ Cc, float* __restrict__ Ss)
{
  __shared__ float xr[768], ct[768], st[768];
  int blk = blockIdx.x;                       // layer*20 + p
  const float* src = prompts + (size_t)blk * 768;
  for (int c = threadIdx.x; c < 768; c += 256) {
    xr[c] = src[c];
    float ang = (float)c * (6.2831853071795864f / 768.f);
    float sv, cv; sincosf(ang, &sv, &cv);
    ct[c] = cv; st[c] = sv;
  }
  __syncthreads();
  for (int k = threadIdx.x; k < 768; k += 256) {
    float cs = 0.f, sn = 0.f; int idx = 0;
    for (int d = 0; d < 768; d++) {
      float xv = xr[d];
      cs += xv * ct[idx];
      sn += xv * st[idx];
      idx += k; if (idx >= 768) idx -= 768;
    }
    Cc[(size_t)blk * 768 + k] = cs;
    Ss[(size_t)blk * 768 + k] = sn;
  }
}

__global__ __launch_bounds__(256) void fft_stage2(const float* __restrict__ Cc, const float* __restrict__ Ss,
                                                  float* __restrict__ pr)
{
  int blk = blockIdx.x; int layer = blk / 20, q = blk % 20;
  __shared__ float tc[20], tsn[20];
  if (threadIdx.x < 20) {
    int j = threadIdx.x;
    float ang = (float)((q * j) % 20) * (6.2831853071795864f / 20.f);
    float sv, cv; sincosf(ang, &sv, &cv);
    tc[j] = cv; tsn[j] = sv;
  }
  __syncthreads();
  for (int k = threadIdx.x; k < 768; k += 256) {
    float acc = 0.f;
    #pragma unroll
    for (int p2 = 0; p2 < 20; p2++) {
      size_t off = ((size_t)(layer * 20 + p2)) * 768 + k;
      acc += Cc[off] * tc[p2] - Ss[off] * tsn[p2];
    }
    pr[((size_t)(layer * 20 + q)) * 768 + k] = acc;
  }
}

// ---------------- LayerNorms ------------------------------------------------------
__global__ __launch_bounds__(256) void ln1_kernel(
    const float* __restrict__ h, const float* __restrict__ pr,
    const float* __restrict__ g, const float* __restrict__ bb,
    short* __restrict__ outp)
{
  int wave = threadIdx.x >> 6, lane = threadIdx.x & 63;
  int row = blockIdx.x * 4 + wave;            // < 13888
  int b = row / CNF, t = row % CNF;
  const float* src;
  if (t == 0) src = h + (size_t)(b * CNT) * CD;
  else if (t <= CP) src = pr + (size_t)(t - 1) * CD;
  else src = h + (size_t)(b * CNT + (t - CP)) * CD;
  float4 v[3];
  float s = 0.f, sq = 0.f;
  #pragma unroll
  for (int j = 0; j < 3; j++) {
    v[j] = *(const float4*)(src + (lane + 64 * j) * 4);
    s += v[j].x + v[j].y + v[j].z + v[j].w;
    sq += v[j].x * v[j].x + v[j].y * v[j].y + v[j].z * v[j].z + v[j].w * v[j].w;
  }
  #pragma unroll
  for (int m = 1; m < 64; m <<= 1) { s += __shfl_xor(s, m); sq += __shfl_xor(sq, m); }
  float mean = s * (1.f / 768.f);
  float var = sq * (1.f / 768.f) - mean * mean;
  float rs = rsqrtf(var + 1e-6f);
  short* orow = outp + (size_t)row * CD;
  #pragma unroll
  for (int j = 0; j < 3; j++) {
    int c = (lane + 64 * j) * 4;
    float4 gg = *(const float4*)(g + c);
    float4 bv = *(const float4*)(bb + c);
    short4v o;
    o.x = f2b((v[j].x - mean) * rs * gg.x + bv.x);
    o.y = f2b((v[j].y - mean) * rs * gg.y + bv.y);
    o.z = f2b((v[j].z - mean) * rs * gg.z + bv.z);
    o.w = f2b((v[j].w - mean) * rs * gg.w + bv.w);
    *(short4v*)(orow + c) = o;
  }
}

__global__ __launch_bounds__(256) void ln2_kernel(
    const float* __restrict__ h, const float* __restrict__ g, const float* __restrict__ bb,
    short* __restrict__ outp)
{
  int wave = threadIdx.x >> 6, lane = threadIdx.x & 63;
  int row = blockIdx.x * 4 + wave;            // < 12608
  const float* src = h + (size_t)row * CD;
  float4 v[3];
  float s = 0.f, sq = 0.f;
  #pragma unroll
  for (int j = 0; j < 3; j++) {
    v[j] = *(const float4*)(src + (lane + 64 * j) * 4);
    s += v[j].x + v[j].y + v[j].z + v[j].w;
    sq += v[j].x * v[j].x + v[j].y * v[j].y + v[j].z * v[j].z + v[j].w * v[j].w;
  }
  #pragma unroll
  for (int m = 1; m < 64; m <<= 1) { s += __shfl_xor(s, m); sq += __shfl_xor(sq, m); }
  float mean = s * (1.f / 768.f);
  float var = sq * (1.f / 768.f) - mean * mean;
  float rs = rsqrtf(var + 1e-6f);
  short* orow = outp + (size_t)row * CD;
  #pragma unroll
  for (int j = 0; j < 3; j++) {
    int c = (lane + 64 * j) * 4;
    float4 gg = *(const float4*)(g + c);
    float4 bv = *(const float4*)(bb + c);
    short4v o;
    o.x = f2b((v[j].x - mean) * rs * gg.x + bv.x);
    o.y = f2b((v[j].y - mean) * rs * gg.y + bv.y);
    o.z = f2b((v[j].z - mean) * rs * gg.z + bv.z);
    o.w = f2b((v[j].w - mean) * rs * gg.w + bv.w);
    *(short4v*)(orow + c) = o;
  }
}

// ---------------- fused attention v3b: K in LDS (swizzled via gload_lds src-permute),
// V^T in LDS (swizzled, scratch-free staging), swapped QK^T, in-register softmax/P.
__global__ __launch_bounds__(256, 2) void attn_kernel(
    const short* __restrict__ qkv, const float* __restrict__ aw,
    const float* __restrict__ ab, const float* __restrict__ mask,
    short* __restrict__ o)
{
  __shared__ short Ks[224 * 64];       // [key][d], row 128 B, chunk-swizzled
  __shared__ short Vt[64 * 256];       // [d][token], row 512 B, chunk-swizzled
  __shared__ float ms[224];
  const int hh = blockIdx.x, b = blockIdx.y;
  const int tid = threadIdx.x, wave = tid >> 6, lane = tid & 63;
  const int lrow = lane & 15, lk = lane >> 4;
  char* const Ks_c = (char*)Ks;
  char* const Vt_c = (char*)Vt;

  for (int t = tid; t < 224; t += 256) ms[t] = (t < CNF) ? mask[t] : 0.f;

  // ---- K staging: global_load_lds, linear dest, source chunk pre-swizzled ------
  {
    const int t = tid >> 3;                        // row within 32-row chunk
    #pragma unroll
    for (int it = 0; it < 7; it++) {
      int row = it * 32 + t;                       // true dest row
      int f = (row ^ (row >> 3)) & 7;
      int rc = row < CNF ? row : CNF - 1;          // clamp (rows >=217 masked later)
      const short* src = qkv + ((size_t)(b * CNF + rc)) * 2304 + 768 + hh * 64 + (((tid & 7) ^ f) << 3);
      gload_lds16(src, (short*)(Ks_c + (it * 256 + wave * 64) * 16));
    }
  }

  // ---- V staging: reg-only (no arrays), scalar swizzled ds_write ---------------
  for (int idx = tid; idx < 224 * 8; idx += 256) {
    int t = idx >> 3, c8 = (idx & 7) * 8;
    unsigned w0 = 0, w1 = 0, w2 = 0, w3 = 0;
    if (t < CNF) {
      uint4 val = *(const uint4*)(qkv + ((size_t)(b * CNF + t)) * 2304 + 1536 + hh * 64 + c8);
      w0 = val.x; w1 = val.y; w2 = val.z; w3 = val.w;
    }
    float f0 = b2fu(w0 & 0xffffu), f1 = b2fu(w0 >> 16);
    float f2 = b2fu(w1 & 0xffffu), f3 = b2fu(w1 >> 16);
    float f4 = b2fu(w2 & 0xffffu), f5 = b2fu(w2 >> 16);
    float f6 = b2fu(w3 & 0xffffu), f7 = b2fu(w3 >> 16);
    if (t >= 1 && t <= CP) {
      const float* awp = aw + (size_t)(t - 1) * CD + hh * 64 + c8;
      const float* abp = ab + (size_t)(t - 1) * CD + hh * 64 + c8;
      float4 a0 = *(const float4*)awp, a1 = *(const float4*)(awp + 4);
      float4 b0 = *(const float4*)abp, b1 = *(const float4*)(abp + 4);
      f0 = f0 * a0.x + b0.x; f1 = f1 * a0.y + b0.y;
      f2 = f2 * a0.z + b0.z; f3 = f3 * a0.w + b0.w;
      f4 = f4 * a1.x + b1.x; f5 = f5 * a1.y + b1.y;
      f6 = f6 * a1.z + b1.z; f7 = f7 * a1.w + b1.w;
    }
    const int tb = 2 * t;
    const int d0 = c8;
    #pragma unroll
    for (int w = 0; w < 8; w++) {
      int d = d0 + w;
      int fsw = ((d ^ (d >> 3)) & 7) << 4;
      float fv = (w == 0) ? f0 : (w == 1) ? f1 : (w == 2) ? f2 : (w == 3) ? f3
               : (w == 4) ? f4 : (w == 5) ? f5 : (w == 6) ? f6 : f7;
      *(short*)(Vt_c + ((d * 512 + tb) ^ fsw)) = f2b(fv);
    }
  }
  __syncthreads();

  const short* qkbase = qkv + (size_t)b * CNF * 2304 + hh * 64;
  const f32x4 zf = {0.f, 0.f, 0.f, 0.f};

  for (int pi = wave; pi < 14; pi += 4) {
    // ---- QK^T (swapped): K rows from LDS (A-operand), Q from global (B) ---------
    int q = pi * 16 + lrow; if (q > CNF - 1) q = CNF - 1;
    const short* qb = qkbase + (size_t)q * 2304;
    bf16x8 bq0 = *(const bf16x8*)(qb + lk * 8);
    bf16x8 bq1 = *(const bf16x8*)(qb + 32 + lk * 8);

    f32x4 p[14];
    #pragma unroll
    for (int nf = 0; nf < 14; nf++) {
      int key = nf * 16 + lrow;
      int fk = (key ^ (key >> 3)) & 7;
      const char* kb = Ks_c + key * 128;
      bf16x8 ak0 = *(const bf16x8*)(kb + ((lk ^ fk) << 4));
      bf16x8 ak1 = *(const bf16x8*)(kb + (((4 + lk) ^ fk) << 4));
      f32x4 acc = zf;
      acc = __builtin_amdgcn_mfma_f32_16x16x32_bf16(ak0, bq0, acc, 0, 0, 0);
      acc = __builtin_amdgcn_mfma_f32_16x16x32_bf16(ak1, bq1, acc, 0, 0, 0);
      p[nf] = acc;
    }

    // ---- softmax over keys (4-lane group reduce) --------------------------------
    float mx = -3.0e38f;
    #pragma unroll
    for (int nf = 0; nf < 14; nf++)
      #pragma unroll
      for (int r = 0; r < 4; r++) {
        int T = nf * 16 + lk * 4 + r;
        float v = p[nf][r] * CSCALE;
        v = (T < CNF) ? v : -3.0e38f;
        p[nf][r] = v;
        mx = fmaxf(mx, v);
      }
    mx = fmaxf(mx, __shfl_xor(mx, 16));
    mx = fmaxf(mx, __shfl_xor(mx, 32));
    float sum = 0.f;
    #pragma unroll
    for (int nf = 0; nf < 14; nf++)
      #pragma unroll
      for (int r = 0; r < 4; r++) {
        float e = exp2f((p[nf][r] - mx) * 1.44269504f);
        p[nf][r] = e; sum += e;
      }
    sum += __shfl_xor(sum, 16);
    sum += __shfl_xor(sum, 32);
    float inv = 1.f / sum;

    // ---- normalize * mask, pack to 2xbf16 words ---------------------------------
    unsigned W01[14], W23[14];
    #pragma unroll
    for (int nf = 0; nf < 14; nf++) {
      int T = nf * 16 + lk * 4;
      float p0 = p[nf][0] * inv * ms[T];
      float p1 = p[nf][1] * inv * ms[T + 1];
      float p2 = p[nf][2] * inv * ms[T + 2];
      float p3 = p[nf][3] * inv * ms[T + 3];
      W01[nf] = pack2(p0, p1);
      W23[nf] = pack2(p2, p3);
    }

    // ---- PV: shuffle P^T -> P A-fragments, MFMA against V^T from LDS ------------
    f32x4 oa[4];
    #pragma unroll
    for (int ni = 0; ni < 4; ni++) oa[ni] = zf;
    const int base = lrow + (lk & 1) * 32;
    const bool hi = lk >= 2;
    #pragma unroll
    for (int kt = 0; kt < 7; kt++) {
      unsigned wa, wb, w0, w1, w2, w3;
      wa = (unsigned)__shfl((int)W01[2 * kt], base);
      wb = (unsigned)__shfl((int)W01[2 * kt + 1], base);
      w0 = hi ? wb : wa;
      wa = (unsigned)__shfl((int)W23[2 * kt], base);
      wb = (unsigned)__shfl((int)W23[2 * kt + 1], base);
      w1 = hi ? wb : wa;
      wa = (unsigned)__shfl((int)W01[2 * kt], base + 16);
      wb = (unsigned)__shfl((int)W01[2 * kt + 1], base + 16);
      w2 = hi ? wb : wa;
      wa = (unsigned)__shfl((int)W23[2 * kt], base + 16);
      wb = (unsigned)__shfl((int)W23[2 * kt + 1], base + 16);
      w3 = hi ? wb : wa;
      uint4 wv; wv.x = w0; wv.y = w1; wv.z = w2; wv.w = w3;
      bf16x8 pa = __builtin_bit_cast(bf16x8, wv);
      #pragma unroll
      for (int ni = 0; ni < 4; ni++) {
        int d = ni * 16 + lrow;
        int fv = ((d ^ (d >> 3)) & 7) << 4;
        bf16x8 bv = *(const bf16x8*)(Vt_c + ((d * 512 + ((kt * 4 + lk) << 4)) ^ fv));
        oa[ni] = __builtin_amdgcn_mfma_f32_16x16x32_bf16(pa, bv, oa[ni], 0, 0, 0);
      }
    }

    // ---- store (drop prompt query rows) -----------------------------------------
    #pragma unroll
    for (int ni = 0; ni < 4; ni++)
      #pragma unroll
      for (int r = 0; r < 4; r++) {
        int qq = pi * 16 + lk * 4 + r;
        int qo;
        if (qq == 0) qo = 0;
        else if (qq >= 1 + CP && qq < CNF) qo = qq - CP;
        else continue;
        o[((size_t)(b * CNT + qo)) * CD + hh * 64 + ni * 16 + lrow] = f2b(oa[ni][r]);
      }
  }
}

// ---------------- final LN + head -------------------------------------------------
__global__ __launch_bounds__(256) void head_kernel(
    const float* __restrict__ h, const float* __restrict__ g, const float* __restrict__ bb,
    const float* __restrict__ hw, const float* __restrict__ hb, float* __restrict__ out)
{
  __shared__ float xn[768];
  __shared__ float ws1[4], ws2[4];
  int b = blockIdx.x;
  const float* src = h + (size_t)(b * CNT) * CD;
  int tidx = threadIdx.x;
  int wave = tidx >> 6, lane = tidx & 63;
  float vv[3];
  float s = 0.f, sq = 0.f;
  #pragma unroll
  for (int j = 0; j < 3; j++) { float xv = src[tidx + 256 * j]; vv[j] = xv; s += xv; sq += xv * xv; }
  #pragma unroll
  for (int m = 1; m < 64; m <<= 1) { s += __shfl_xor(s, m); sq += __shfl_xor(sq, m); }
  if (lane == 0) { ws1[wave] = s; ws2[wave] = sq; }
  __syncthreads();
  s = ws1[0] + ws1[1] + ws1[2] + ws1[3];
  sq = ws2[0] + ws2[1] + ws2[2] + ws2[3];
  float mean = s * (1.f / 768.f);
  float var = sq * (1.f / 768.f) - mean * mean;
  float rs = rsqrtf(var + 1e-6f);
  #pragma unroll
  for (int j = 0; j < 3; j++) { int c = tidx + 256 * j; xn[c] = (vv[j] - mean) * rs * g[c] + bb[c]; }
  __syncthreads();
  if (tidx < CNCLS) {
    float acc = hb[tidx];
    for (int d = 0; d < 768; d++) acc += xn[d] * hw[d * CNCLS + tidx];
    out[b * CNCLS + tidx] = acc;
  }
}

// ---------------- host ------------------------------------------------------------
static inline int gemm_grid(int M, int N, int MCH){
  int nm = (M + 127) >> 7;
  int nch = (nm + MCH - 1) / MCH;
  return nch * MCH * (N >> 7);
}

extern "C" void kernel_launch(void* const* d_in, const int* in_sizes, int n_in,
                              void* d_out, int out_size, void* d_ws, size_t ws_size,
                              hipStream_t stream)
{
  (void)in_sizes; (void)n_in; (void)out_size; (void)ws_size;
  const float* x       = (const float*)d_in[0];
  const float* patch_w = (const float*)d_in[1];
  const float* patch_b = (const float*)d_in[2];
  const float* cls_tok = (const float*)d_in[3];
  const float* pos     = (const float*)d_in[4];
  const float* prompts = (const float*)d_in[5];
  const float* masks   = (const float*)d_in[6];
  const float* advp_w  = (const float*)d_in[7];
  const float* advp_b  = (const float*)d_in[8];
  const float* ln1_g   = (const float*)d_in[9];
  const float* ln1_b   = (const float*)d_in[10];
  const float* qkv_w   = (const float*)d_in[11];
  const float* qkv_b   = (const float*)d_in[12];
  const float* proj_w  = (const float*)d_in[13];
  const float* proj_b  = (const float*)d_in[14];
  const float* ln2_g   = (const float*)d_in[15];
  const float* ln2_b   = (const float*)d_in[16];
  const float* fc1_w   = (const float*)d_in[17];
  const float* fc1_b   = (const float*)d_in[18];
  const float* fc2_w   = (const float*)d_in[19];
  const float* fc2_b   = (const float*)d_in[20];
  const float* norm_g  = (const float*)d_in[21];
  const float* norm_b  = (const float*)d_in[22];
  const float* head_w  = (const float*)d_in[23];
  const float* head_b  = (const float*)d_in[24];
  float* out = (float*)d_out;

  char* wsp = (char*)d_ws;
  auto alloc = [&](size_t bytes) -> void* {
    void* r = (void*)wsp; wsp += (bytes + 255) & ~(size_t)255; return r;
  };
  short* wq     = (short*)alloc((size_t)2304 * 768 * 2);
  short* wp     = (short*)alloc((size_t)768 * 768 * 2);
  short* w1     = (short*)alloc((size_t)3072 * 768 * 2);
  short* w2     = (short*)alloc((size_t)768 * 3072 * 2);
  short* wpatch = (short*)alloc((size_t)768 * 768 * 2);
  short* Pm     = (short*)alloc((size_t)12544 * 768 * 2);
  float* h      = (float*)alloc((size_t)12608 * 768 * 4);
  short* a_in   = (short*)alloc((size_t)13952 * 768 * 2);
  short* qkv    = (short*)alloc((size_t)13952 * 2304 * 2);
  short* ob     = (short*)alloc((size_t)12672 * 768 * 2);
  short* mb     = (short*)alloc((size_t)12672 * 768 * 2);
  short* g1     = (short*)alloc((size_t)12672 * 3072 * 2);
  float* Cc     = (float*)alloc((size_t)240 * 768 * 4);
  float* Ss     = (float*)alloc((size_t)240 * 768 * 4);
  float* pr     = (float*)alloc((size_t)240 * 768 * 4);

  fft_stage1<<<240, 256, 0, stream>>>(prompts, Cc, Ss);
  fft_stage2<<<240, 256, 0, stream>>>(Cc, Ss, pr);
  patch_build<<<37632, 256, 0, stream>>>(x, Pm);
  wtrans<<<dim3(24, 24), dim3(32, 8), 0, stream>>>(patch_w, wpatch, 768, 768);
  gemm_bt<3><<<gemm_grid(12544, 768, 8), 256, 0, stream>>>(Pm, wpatch, patch_b, nullptr, h, pos, 12544, 768, 768, 8);
  cls_pos<<<192, 256, 0, stream>>>(cls_tok, pos, h);

  for (int i = 0; i < CL; i++) {
    ln1_kernel<<<3472, 256, 0, stream>>>(h, pr + (size_t)i * 20 * 768, ln1_g + i * 768, ln1_b + i * 768, a_in);
    wtrans<<<dim3(24, 72), dim3(32, 8), 0, stream>>>(qkv_w + (size_t)i * 768 * 2304, wq, 768, 2304);
    gemm_bt<0><<<gemm_grid(13888, 2304, 8), 256, 0, stream>>>(a_in, wq, qkv_b + i * 2304, qkv, nullptr, nullptr, 13888, 2304, 768, 8);
    attn_kernel<<<dim3(12, 64), 256, 0, stream>>>(qkv, advp_w, advp_b, masks + i * CNF, ob);
    wtrans<<<dim3(24, 24), dim3(32, 8), 0, stream>>>(proj_w + (size_t)i * 768 * 768, wp, 768, 768);
    gemm_bt<2><<<gemm_grid(12608, 768, 8), 256, 0, stream>>>(ob, wp, proj_b + i * 768, nullptr, h, nullptr, 12608, 768, 768, 8);
    ln2_kernel<<<3152, 256, 0, stream>>>(h, ln2_g + i * 768, ln2_b + i * 768, mb);
    wtrans<<<dim3(24, 96), dim3(32, 8), 0, stream>>>(fc1_w + (size_t)i * 768 * 3072, w1, 768, 3072);
    gemm_bt<1><<<gemm_grid(12608, 3072, 8), 256, 0, stream>>>(mb, w1, fc1_b + i * 3072, g1, nullptr, nullptr, 12608, 3072, 768, 8);
    wtrans<<<dim3(96, 24), dim3(32, 8), 0, stream>>>(fc2_w + (size_t)i * 3072 * 768, w2, 3072, 768);
    gemm_bt<2><<<gemm_grid(12608, 768, 4), 256, 0, stream>>>(g1, w2, fc2_b + i * 768, nullptr, h, nullptr, 12608, 768, 3072, 4);
  }
  head_kernel<<<64, 256, 0, stream>>>(h, norm_g, norm_b, head_w, head_b, out);
}

// Round 7
// 5857.822 us; speedup vs baseline: 1.2706x; 1.0032x over previous
//
#include <hip/hip_runtime.h>
#include <hip/hip_bf16.h>
#include <cstdint>

constexpr int CL = 12, CH = 12, CD = 768, CP = 20, CNT = 197, CNF = 217, CB = 64, CNCLS = 100;
constexpr float CSCALE = 0.125f;

typedef __bf16 bf16x8 __attribute__((ext_vector_type(8)));
typedef float f32x4 __attribute__((ext_vector_type(4)));
typedef short short4v __attribute__((ext_vector_type(4)));

__device__ __forceinline__ short f2b(float f){
  uint32_t x = __builtin_bit_cast(uint32_t, f);
  x = (x + 0x7fffu + ((x >> 16) & 1u)) >> 16;
  return (short)x;
}
__device__ __forceinline__ float b2f(short s){
  return __builtin_bit_cast(float, ((uint32_t)(uint16_t)s) << 16);
}
__device__ __forceinline__ float b2fu(unsigned u){   // low 16 bits = bf16
  return __builtin_bit_cast(float, u << 16);
}
__device__ __forceinline__ unsigned pack2(float lo, float hi){
  return (unsigned)(uint16_t)f2b(lo) | ((unsigned)(uint16_t)f2b(hi) << 16);
}
__device__ __forceinline__ void gload_lds16(const short* g, short* l){
  __builtin_amdgcn_global_load_lds((const __attribute__((address_space(1))) void*)g,
                                   (__attribute__((address_space(3))) void*)l, 16, 0, 0);
}

// ---------------- GEMM v2: 2-phase pipelined, L2-chunked, XCD-swizzled --------------
// C[M,N] = A[M,K](bf16) * Bt[N,K]^T(bf16) + bias. 1-D grid = nch*MCH*(N/128).
// EPI 0: bias -> planar qkv store [sel][b][h][t][64]; 1: bias+gelu -> bf16;
// EPI 2: bias + add into fp32 Cf; 3: patch remap (bias+pos -> Cf)
template<int EPI>
__global__ __launch_bounds__(256, 2) void gemm_bt(
    const short* __restrict__ A, const short* __restrict__ Bt,
    const float* __restrict__ bias, short* __restrict__ Cb,
    float* __restrict__ Cf, const float* __restrict__ pos,
    int M, int N, int K, int MCH)
{
  __shared__ short As[2][128 * 32];
  __shared__ short Bs[2][128 * 32];
  const int tid = threadIdx.x;
  const int wave = tid >> 6, lane = tid & 63;
  const int wr = wave >> 1, wc = wave & 1;
  const int lrow = lane & 15, lk = lane >> 4;

  // --- bijective XCD swizzle (m204) + chunked decomposition (inner-M fastest) ----
  const int nwg = gridDim.x;
  const int orig = blockIdx.x;
  const int q = nwg >> 3, r = nwg & 7;
  const int xcd = orig & 7, lid = orig >> 3;
  const int flat = (xcd < r ? xcd * (q + 1) : r * (q + 1) + (xcd - r) * q) + lid;
  const int nn = N >> 7;
  const int per = MCH * nn;
  const int c0 = flat / per, rem = flat - c0 * per;
  const int n  = rem / MCH, im = rem - (rem / MCH) * MCH;
  const int mp = c0 * MCH + im;
  const int m0 = mp << 7, n0 = n << 7;
  if (m0 >= M) return;

  f32x4 zf = {0.f, 0.f, 0.f, 0.f};
  f32x4 acc[4][4];
  #pragma unroll
  for (int i = 0; i < 4; i++)
    #pragma unroll
    for (int j = 0; j < 4; j++) acc[i][j] = zf;

  auto STAGE = [&](int buf, int k0) {
    #pragma unroll
    for (int i = 0; i < 2; i++) {
      int idx = i * 256 + tid;
      int row = idx >> 2, c8 = (idx & 3) * 8;
      int gra = m0 + row; gra = gra < M ? gra : M - 1;
      gload_lds16(A + (size_t)gra * K + k0 + c8,
                  (short*)((char*)As + buf * 8192 + (i * 256 + wave * 64) * 16));
      int grb = n0 + row;
      gload_lds16(Bt + (size_t)grb * K + k0 + c8,
                  (short*)((char*)Bs + buf * 8192 + (i * 256 + wave * 64) * 16));
    }
  };

  STAGE(0, 0);
  __syncthreads();
  const int nt = K >> 5;
  for (int t = 0; t < nt; t++) {
    const int cur = t & 1;
    if (t + 1 < nt) STAGE(cur ^ 1, (t + 1) << 5);
    const short* pA = As[cur] + (wr * 64 + lrow) * 32 + lk * 8;
    const short* pB = Bs[cur] + (wc * 64 + lrow) * 32 + lk * 8;
    bf16x8 af[4], bfv[4];
    #pragma unroll
    for (int mi = 0; mi < 4; mi++) af[mi] = *(const bf16x8*)(pA + mi * 16 * 32);
    #pragma unroll
    for (int ni = 0; ni < 4; ni++) bfv[ni] = *(const bf16x8*)(pB + ni * 16 * 32);
    #pragma unroll
    for (int mi = 0; mi < 4; mi++)
      #pragma unroll
      for (int ni = 0; ni < 4; ni++)
        acc[mi][ni] = __builtin_amdgcn_mfma_f32_16x16x32_bf16(af[mi], bfv[ni], acc[mi][ni], 0, 0, 0);
    __syncthreads();
  }

  #pragma unroll
  for (int mi = 0; mi < 4; mi++) {
    int rbase = m0 + wr * 64 + mi * 16 + lk * 4;
    #pragma unroll
    for (int ni = 0; ni < 4; ni++) {
      int col = n0 + wc * 64 + ni * 16 + lrow;
      float bv = bias[col];
      f32x4 v = acc[mi][ni];
      #pragma unroll
      for (int r2 = 0; r2 < 4; r2++) {
        int row = rbase + r2;
        if (row >= M) continue;
        float val = v[r2] + bv;
        if constexpr (EPI == 0) {
          // planar qkv: row = b*217 + t; col = sel*768 + h*64 + d
          int bq = row / CNF, t2 = row - bq * CNF;
          int sel = col / CD, hd = col - sel * CD;
          int hh2 = hd >> 6, dd = hd & 63;
          Cb[(((size_t)(sel * CB + bq) * CH + hh2) * CNF + t2) * 64 + dd] = f2b(val);
        } else if constexpr (EPI == 1) {
          float g = 0.5f * val * (1.0f + erff(val * 0.70710678118f));
          Cb[(size_t)row * N + col] = f2b(g);
        } else if constexpr (EPI == 2) {
          Cf[(size_t)row * N + col] += val;
        } else {
          int b = row / 196, pp = row % 196;
          Cf[((size_t)(b * CNT + 1 + pp)) * CD + col] = val + pos[(1 + pp) * CD + col];
        }
      }
    }
  }
}

// ---------------- weight transpose + bf16 convert: in[K,N] f32 -> out[N,K] bf16 ------
__global__ void wtrans(const float* __restrict__ in, short* __restrict__ out, int K, int N)
{
  __shared__ float t[32][33];
  int tx = threadIdx.x, ty = threadIdx.y;
  int k0 = blockIdx.x * 32, n0 = blockIdx.y * 32;
  for (int i = ty; i < 32; i += 8)
    t[i][tx] = in[(size_t)(k0 + i) * N + n0 + tx];
  __syncthreads();
  for (int i = ty; i < 32; i += 8)
    out[(size_t)(n0 + i) * K + k0 + tx] = f2b(t[tx][i]);
}

// ---------------- patch matrix build: x[B,3,224,224] -> Pm[B*196, 768] bf16 ---------
__global__ void patch_build(const float* __restrict__ x, short* __restrict__ Pm)
{
  int idx = blockIdx.x * 256 + threadIdx.x;   // < 12544*768
  int r = idx / 768, c = idx % 768;
  int b = r / 196, np = r % 196;
  int gy = np / 14, gx = np % 14;
  int ch = c >> 8, rem = c & 255, py = rem >> 4, px = rem & 15;
  float v = x[((size_t)(b * 3 + ch) * 224 + gy * 16 + py) * 224 + gx * 16 + px];
  Pm[idx] = f2b(v);
}

__global__ void cls_pos(const float* __restrict__ cls, const float* __restrict__ pos, float* __restrict__ h)
{
  int idx = blockIdx.x * 256 + threadIdx.x;   // < 64*768
  int b = idx / 768, c = idx % 768;
  h[(size_t)(b * CNT) * CD + c] = cls[c] + pos[c];
}

// ---------------- FFT(prompts) real part, separable, all layers --------------------
__global__ __launch_bounds__(256) void fft_stage1(const float* __restrict__ prompts,
                                                  float* __restrict__ Cc, float* __restrict__ Ss)
{
  __shared__ float xr[768], ct[768], st[768];
  int blk = blockIdx.x;                       // layer*20 + p
  const float* src = prompts + (size_t)blk * 768;
  for (int c = threadIdx.x; c < 768; c += 256) {
    xr[c] = src[c];
    float ang = (float)c * (6.2831853071795864f / 768.f);
    float sv, cv; sincosf(ang, &sv, &cv);
    ct[c] = cv; st[c] = sv;
  }
  __syncthreads();
  for (int k = threadIdx.x; k < 768; k += 256) {
    float cs = 0.f, sn = 0.f; int idx = 0;
    for (int d = 0; d < 768; d++) {
      float xv = xr[d];
      cs += xv * ct[idx];
      sn += xv * st[idx];
      idx += k; if (idx >= 768) idx -= 768;
    }
    Cc[(size_t)blk * 768 + k] = cs;
    Ss[(size_t)blk * 768 + k] = sn;
  }
}

__global__ __launch_bounds__(256) void fft_stage2(const float* __restrict__ Cc, const float* __restrict__ Ss,
                                                  float* __restrict__ pr)
{
  int blk = blockIdx.x; int layer = blk / 20, q = blk % 20;
  __shared__ float tc[20], tsn[20];
  if (threadIdx.x < 20) {
    int j = threadIdx.x;
    float ang = (float)((q * j) % 20) * (6.2831853071795864f / 20.f);
    float sv, cv; sincosf(ang, &sv, &cv);
    tc[j] = cv; tsn[j] = sv;
  }
  __syncthreads();
  for (int k = threadIdx.x; k < 768; k += 256) {
    float acc = 0.f;
    #pragma unroll
    for (int p2 = 0; p2 < 20; p2++) {
      size_t off = ((size_t)(layer * 20 + p2)) * 768 + k;
      acc += Cc[off] * tc[p2] - Ss[off] * tsn[p2];
    }
    pr[((size_t)(layer * 20 + q)) * 768 + k] = acc;
  }
}

// ---------------- LayerNorms ------------------------------------------------------
__global__ __launch_bounds__(256) void ln1_kernel(
    const float* __restrict__ h, const float* __restrict__ pr,
    const float* __restrict__ g, const float* __restrict__ bb,
    short* __restrict__ outp)
{
  int wave = threadIdx.x >> 6, lane = threadIdx.x & 63;
  int row = blockIdx.x * 4 + wave;            // < 13888
  int b = row / CNF, t = row % CNF;
  const float* src;
  if (t == 0) src = h + (size_t)(b * CNT) * CD;
  else if (t <= CP) src = pr + (size_t)(t - 1) * CD;
  else src = h + (size_t)(b * CNT + (t - CP)) * CD;
  float4 v[3];
  float s = 0.f, sq = 0.f;
  #pragma unroll
  for (int j = 0; j < 3; j++) {
    v[j] = *(const float4*)(src + (lane + 64 * j) * 4);
    s += v[j].x + v[j].y + v[j].z + v[j].w;
    sq += v[j].x * v[j].x + v[j].y * v[j].y + v[j].z * v[j].z + v[j].w * v[j].w;
  }
  #pragma unroll
  for (int m = 1; m < 64; m <<= 1) { s += __shfl_xor(s, m); sq += __shfl_xor(sq, m); }
  float mean = s * (1.f / 768.f);
  float var = sq * (1.f / 768.f) - mean * mean;
  float rs = rsqrtf(var + 1e-6f);
  short* orow = outp + (size_t)row * CD;
  #pragma unroll
  for (int j = 0; j < 3; j++) {
    int c = (lane + 64 * j) * 4;
    float4 gg = *(const float4*)(g + c);
    float4 bv = *(const float4*)(bb + c);
    short4v o;
    o.x = f2b((v[j].x - mean) * rs * gg.x + bv.x);
    o.y = f2b((v[j].y - mean) * rs * gg.y + bv.y);
    o.z = f2b((v[j].z - mean) * rs * gg.z + bv.z);
    o.w = f2b((v[j].w - mean) * rs * gg.w + bv.w);
    *(short4v*)(orow + c) = o;
  }
}

__global__ __launch_bounds__(256) void ln2_kernel(
    const float* __restrict__ h, const float* __restrict__ g, const float* __restrict__ bb,
    short* __restrict__ outp)
{
  int wave = threadIdx.x >> 6, lane = threadIdx.x & 63;
  int row = blockIdx.x * 4 + wave;            // < 12608
  const float* src = h + (size_t)row * CD;
  float4 v[3];
  float s = 0.f, sq = 0.f;
  #pragma unroll
  for (int j = 0; j < 3; j++) {
    v[j] = *(const float4*)(src + (lane + 64 * j) * 4);
    s += v[j].x + v[j].y + v[j].z + v[j].w;
    sq += v[j].x * v[j].x + v[j].y * v[j].y + v[j].z * v[j].z + v[j].w * v[j].w;
  }
  #pragma unroll
  for (int m = 1; m < 64; m <<= 1) { s += __shfl_xor(s, m); sq += __shfl_xor(sq, m); }
  float mean = s * (1.f / 768.f);
  float var = sq * (1.f / 768.f) - mean * mean;
  float rs = rsqrtf(var + 1e-6f);
  short* orow = outp + (size_t)row * CD;
  #pragma unroll
  for (int j = 0; j < 3; j++) {
    int c = (lane + 64 * j) * 4;
    float4 gg = *(const float4*)(g + c);
    float4 bv = *(const float4*)(bb + c);
    short4v o;
    o.x = f2b((v[j].x - mean) * rs * gg.x + bv.x);
    o.y = f2b((v[j].y - mean) * rs * gg.y + bv.y);
    o.z = f2b((v[j].z - mean) * rs * gg.z + bv.z);
    o.w = f2b((v[j].w - mean) * rs * gg.w + bv.w);
    *(short4v*)(orow + c) = o;
  }
}

// ---------------- fused attention v4: planar qkv input, K in LDS (swizzled),
// V^T in LDS (swizzled), swapped QK^T, in-reg softmax, PV as O^T = Vt * P^T with
// zero-waste 4-shfl/kt P-exchange, short4 O stores.
__global__ __launch_bounds__(256, 2) void attn_kernel(
    const short* __restrict__ qkvP, const float* __restrict__ aw,
    const float* __restrict__ ab, const float* __restrict__ mask,
    short* __restrict__ o)
{
  __shared__ short Ks[224 * 64];       // [key][d], row 128 B, chunk-swizzled
  __shared__ short Vt[64 * 256];       // [d][token], row 512 B, chunk-swizzled
  __shared__ float ms[224];
  const int hh = blockIdx.x, b = blockIdx.y;
  const int tid = threadIdx.x, wave = tid >> 6, lane = tid & 63;
  const int lrow = lane & 15, lk = lane >> 4;
  const int b4 = lk & 1, b5 = lk >> 1;
  char* const Ks_c = (char*)Ks;
  char* const Vt_c = (char*)Vt;

  const short* Qb = qkvP + ((size_t)(0 * CB + b) * CH + hh) * (CNF * 64);
  const short* Kb = qkvP + ((size_t)(1 * CB + b) * CH + hh) * (CNF * 64);
  const short* Vb = qkvP + ((size_t)(2 * CB + b) * CH + hh) * (CNF * 64);

  for (int t = tid; t < 224; t += 256) ms[t] = (t < CNF) ? mask[t] : 0.f;

  // ---- K staging: global_load_lds, linear dest, source chunk pre-swizzled ------
  {
    const int t = tid >> 3;                        // row within 32-row chunk
    #pragma unroll
    for (int it = 0; it < 7; it++) {
      int row = it * 32 + t;                       // true dest row
      int f = (row ^ (row >> 3)) & 7;
      int rc = row < CNF ? row : CNF - 1;
      gload_lds16(Kb + rc * 64 + (((tid & 7) ^ f) << 3),
                  (short*)(Ks_c + (it * 256 + wave * 64) * 16));
    }
  }

  // ---- V staging: reg-only, scalar swizzled ds_write ---------------------------
  for (int idx = tid; idx < 224 * 8; idx += 256) {
    int t = idx >> 3, c8 = (idx & 7) * 8;
    unsigned w0 = 0, w1 = 0, w2 = 0, w3 = 0;
    if (t < CNF) {
      uint4 val = *(const uint4*)(Vb + t * 64 + c8);
      w0 = val.x; w1 = val.y; w2 = val.z; w3 = val.w;
    }
    float f0 = b2fu(w0 & 0xffffu), f1 = b2fu(w0 >> 16);
    float f2 = b2fu(w1 & 0xffffu), f3 = b2fu(w1 >> 16);
    float f4 = b2fu(w2 & 0xffffu), f5 = b2fu(w2 >> 16);
    float f6 = b2fu(w3 & 0xffffu), f7 = b2fu(w3 >> 16);
    if (t >= 1 && t <= CP) {
      const float* awp = aw + (size_t)(t - 1) * CD + hh * 64 + c8;
      const float* abp = ab + (size_t)(t - 1) * CD + hh * 64 + c8;
      float4 a0 = *(const float4*)awp, a1 = *(const float4*)(awp + 4);
      float4 b0 = *(const float4*)abp, b1 = *(const float4*)(abp + 4);
      f0 = f0 * a0.x + b0.x; f1 = f1 * a0.y + b0.y;
      f2 = f2 * a0.z + b0.z; f3 = f3 * a0.w + b0.w;
      f4 = f4 * a1.x + b1.x; f5 = f5 * a1.y + b1.y;
      f6 = f6 * a1.z + b1.z; f7 = f7 * a1.w + b1.w;
    }
    const int tb = 2 * t;
    const int d0 = c8;
    #pragma unroll
    for (int w = 0; w < 8; w++) {
      int d = d0 + w;
      int fsw = ((d ^ (d >> 3)) & 7) << 4;
      float fv = (w == 0) ? f0 : (w == 1) ? f1 : (w == 2) ? f2 : (w == 3) ? f3
               : (w == 4) ? f4 : (w == 5) ? f5 : (w == 6) ? f6 : f7;
      *(short*)(Vt_c + ((d * 512 + tb) ^ fsw)) = f2b(fv);
    }
  }
  __syncthreads();

  const f32x4 zf = {0.f, 0.f, 0.f, 0.f};

  for (int pi = wave; pi < 14; pi += 4) {
    // ---- QK^T (swapped): K rows from LDS (A-operand), Q from global (B) ---------
    int q = pi * 16 + lrow; int qc = q < CNF ? q : CNF - 1;
    const short* qb = Qb + (size_t)qc * 64;
    bf16x8 bq0 = *(const bf16x8*)(qb + lk * 8);
    bf16x8 bq1 = *(const bf16x8*)(qb + 32 + lk * 8);

    f32x4 p[14];
    __builtin_amdgcn_s_setprio(1);
    #pragma unroll
    for (int nf = 0; nf < 14; nf++) {
      int key = nf * 16 + lrow;
      int fk = (key ^ (key >> 3)) & 7;
      const char* kb = Ks_c + key * 128;
      bf16x8 ak0 = *(const bf16x8*)(kb + ((lk ^ fk) << 4));
      bf16x8 ak1 = *(const bf16x8*)(kb + (((4 + lk) ^ fk) << 4));
      f32x4 acc = zf;
      acc = __builtin_amdgcn_mfma_f32_16x16x32_bf16(ak0, bq0, acc, 0, 0, 0);
      acc = __builtin_amdgcn_mfma_f32_16x16x32_bf16(ak1, bq1, acc, 0, 0, 0);
      p[nf] = acc;
    }
    __builtin_amdgcn_s_setprio(0);

    // ---- softmax over keys (4-lane group reduce) --------------------------------
    float mx = -3.0e38f;
    #pragma unroll
    for (int nf = 0; nf < 14; nf++)
      #pragma unroll
      for (int r = 0; r < 4; r++) {
        int T = nf * 16 + lk * 4 + r;
        float v = p[nf][r] * CSCALE;
        v = (T < CNF) ? v : -3.0e38f;
        p[nf][r] = v;
        mx = fmaxf(mx, v);
      }
    mx = fmaxf(mx, __shfl_xor(mx, 16));
    mx = fmaxf(mx, __shfl_xor(mx, 32));
    float sum = 0.f;
    #pragma unroll
    for (int nf = 0; nf < 14; nf++)
      #pragma unroll
      for (int r = 0; r < 4; r++) {
        float e = exp2f((p[nf][r] - mx) * 1.44269504f);
        p[nf][r] = e; sum += e;
      }
    sum += __shfl_xor(sum, 16);
    sum += __shfl_xor(sum, 32);
    float inv = 1.f / sum;

    // ---- normalize * mask, pack to 2xbf16 words (P^T rows T=nf*16+lk*4+r, col q) -
    unsigned W01[14], W23[14];
    #pragma unroll
    for (int nf = 0; nf < 14; nf++) {
      int T = nf * 16 + lk * 4;
      float p0 = p[nf][0] * inv * ms[T];
      float p1 = p[nf][1] * inv * ms[T + 1];
      float p2 = p[nf][2] * inv * ms[T + 2];
      float p3 = p[nf][3] * inv * ms[T + 3];
      W01[nf] = pack2(p0, p1);
      W23[nf] = pack2(p2, p3);
    }

    // ---- PV as O^T = mfma(A=Vt, B=P^T): 4-shfl/kt zero-waste exchange -----------
    f32x4 oa[4];
    #pragma unroll
    for (int mi = 0; mi < 4; mi++) oa[mi] = zf;
    const int srcA = lrow + (b5 << 4) + (b4 << 5);  // owner (o4=c5, o5=c4)
    const int srcB = srcA ^ 16;                      // owner (o4=1-c5, o5=c4)
    #pragma unroll
    for (int kt = 0; kt < 7; kt++) {
      unsigned pubA01 = b4 ? W01[2 * kt + 1] : W01[2 * kt];
      unsigned pubB01 = b4 ? W01[2 * kt]     : W01[2 * kt + 1];
      unsigned pubA23 = b4 ? W23[2 * kt + 1] : W23[2 * kt];
      unsigned pubB23 = b4 ? W23[2 * kt]     : W23[2 * kt + 1];
      unsigned gA01 = (unsigned)__shfl((int)pubA01, srcA);
      unsigned gB01 = (unsigned)__shfl((int)pubB01, srcB);
      unsigned gA23 = (unsigned)__shfl((int)pubA23, srcA);
      unsigned gB23 = (unsigned)__shfl((int)pubB23, srcB);
      uint4 pw;
      pw.x = b5 ? gB01 : gA01;   // jj 0,1  (b=0)
      pw.y = b5 ? gB23 : gA23;   // jj 2,3
      pw.z = b5 ? gA01 : gB01;   // jj 4,5  (b=1)
      pw.w = b5 ? gA23 : gB23;   // jj 6,7
      bf16x8 pfrag = __builtin_bit_cast(bf16x8, pw);
      __builtin_amdgcn_s_setprio(1);
      #pragma unroll
      for (int mi = 0; mi < 4; mi++) {
        int d = mi * 16 + lrow;
        int fv = ((d ^ (d >> 3)) & 7) << 4;
        bf16x8 vfrag = *(const bf16x8*)(Vt_c + ((d * 512 + ((kt * 4 + lk) << 4)) ^ fv));
        oa[mi] = __builtin_amdgcn_mfma_f32_16x16x32_bf16(vfrag, pfrag, oa[mi], 0, 0, 0);
      }
      __builtin_amdgcn_s_setprio(0);
    }

    // ---- store O^T: lane owns q = pi*16+lrow, d = mi*16 + lk*4 + r (short4) -----
    int qo = (q == 0) ? 0 : (q >= 1 + CP && q < CNF) ? q - CP : -1;
    if (qo >= 0) {
      short* orow = o + ((size_t)(b * CNT + qo)) * CD + hh * 64;
      #pragma unroll
      for (int mi = 0; mi < 4; mi++) {
        short4v s4;
        s4.x = f2b(oa[mi][0]); s4.y = f2b(oa[mi][1]);
        s4.z = f2b(oa[mi][2]); s4.w = f2b(oa[mi][3]);
        *(short4v*)(orow + mi * 16 + lk * 4) = s4;
      }
    }
  }
}

// ---------------- final LN + head -------------------------------------------------
__global__ __launch_bounds__(256) void head_kernel(
    const float* __restrict__ h, const float* __restrict__ g, const float* __restrict__ bb,
    const float* __restrict__ hw, const float* __restrict__ hb, float* __restrict__ out)
{
  __shared__ float xn[768];
  __shared__ float ws1[4], ws2[4];
  int b = blockIdx.x;
  const float* src = h + (size_t)(b * CNT) * CD;
  int tidx = threadIdx.x;
  int wave = tidx >> 6, lane = tidx & 63;
  float vv[3];
  float s = 0.f, sq = 0.f;
  #pragma unroll
  for (int j = 0; j < 3; j++) { float xv = src[tidx + 256 * j]; vv[j] = xv; s += xv; sq += xv * xv; }
  #pragma unroll
  for (int m = 1; m < 64; m <<= 1) { s += __shfl_xor(s, m); sq += __shfl_xor(sq, m); }
  if (lane == 0) { ws1[wave] = s; ws2[wave] = sq; }
  __syncthreads();
  s = ws1[0] + ws1[1] + ws1[2] + ws1[3];
  sq = ws2[0] + ws2[1] + ws2[2] + ws2[3];
  float mean = s * (1.f / 768.f);
  float var = sq * (1.f / 768.f) - mean * mean;
  float rs = rsqrtf(var + 1e-6f);
  #pragma unroll
  for (int j = 0; j < 3; j++) { int c = tidx + 256 * j; xn[c] = (vv[j] - mean) * rs * g[c] + bb[c]; }
  __syncthreads();
  if (tidx < CNCLS) {
    float acc = hb[tidx];
    for (int d = 0; d < 768; d++) acc += xn[d] * hw[d * CNCLS + tidx];
    out[b * CNCLS + tidx] = acc;
  }
}

// ---------------- host ------------------------------------------------------------
static inline int gemm_grid(int M, int N, int MCH){
  int nm = (M + 127) >> 7;
  int nch = (nm + MCH - 1) / MCH;
  return nch * MCH * (N >> 7);
}

extern "C" void kernel_launch(void* const* d_in, const int* in_sizes, int n_in,
                              void* d_out, int out_size, void* d_ws, size_t ws_size,
                              hipStream_t stream)
{
  (void)in_sizes; (void)n_in; (void)out_size; (void)ws_size;
  const float* x       = (const float*)d_in[0];
  const float* patch_w = (const float*)d_in[1];
  const float* patch_b = (const float*)d_in[2];
  const float* cls_tok = (const float*)d_in[3];
  const float* pos     = (const float*)d_in[4];
  const float* prompts = (const float*)d_in[5];
  const float* masks   = (const float*)d_in[6];
  const float* advp_w  = (const float*)d_in[7];
  const float* advp_b  = (const float*)d_in[8];
  const float* ln1_g   = (const float*)d_in[9];
  const float* ln1_b   = (const float*)d_in[10];
  const float* qkv_w   = (const float*)d_in[11];
  const float* qkv_b   = (const float*)d_in[12];
  const float* proj_w  = (const float*)d_in[13];
  const float* proj_b  = (const float*)d_in[14];
  const float* ln2_g   = (const float*)d_in[15];
  const float* ln2_b   = (const float*)d_in[16];
  const float* fc1_w   = (const float*)d_in[17];
  const float* fc1_b   = (const float*)d_in[18];
  const float* fc2_w   = (const float*)d_in[19];
  const float* fc2_b   = (const float*)d_in[20];
  const float* norm_g  = (const float*)d_in[21];
  const float* norm_b  = (const float*)d_in[22];
  const float* head_w  = (const float*)d_in[23];
  const float* head_b  = (const float*)d_in[24];
  float* out = (float*)d_out;

  char* wsp = (char*)d_ws;
  auto alloc = [&](size_t bytes) -> void* {
    void* r = (void*)wsp; wsp += (bytes + 255) & ~(size_t)255; return r;
  };
  short* wq     = (short*)alloc((size_t)2304 * 768 * 2);
  short* wp     = (short*)alloc((size_t)768 * 768 * 2);
  short* w1     = (short*)alloc((size_t)3072 * 768 * 2);
  short* w2     = (short*)alloc((size_t)768 * 3072 * 2);
  short* wpatch = (short*)alloc((size_t)768 * 768 * 2);
  short* Pm     = (short*)alloc((size_t)12544 * 768 * 2);
  float* h      = (float*)alloc((size_t)12608 * 768 * 4);
  short* a_in   = (short*)alloc((size_t)13952 * 768 * 2);
  short* qkv    = (short*)alloc((size_t)3 * 64 * 12 * 217 * 64 * 2);   // planar [sel][b][h][t][64]
  short* ob     = (short*)alloc((size_t)12672 * 768 * 2);
  short* mb     = (short*)alloc((size_t)12672 * 768 * 2);
  short* g1     = (short*)alloc((size_t)12672 * 3072 * 2);
  float* Cc     = (float*)alloc((size_t)240 * 768 * 4);
  float* Ss     = (float*)alloc((size_t)240 * 768 * 4);
  float* pr     = (float*)alloc((size_t)240 * 768 * 4);

  fft_stage1<<<240, 256, 0, stream>>>(prompts, Cc, Ss);
  fft_stage2<<<240, 256, 0, stream>>>(Cc, Ss, pr);
  patch_build<<<37632, 256, 0, stream>>>(x, Pm);
  wtrans<<<dim3(24, 24), dim3(32, 8), 0, stream>>>(patch_w, wpatch, 768, 768);
  gemm_bt<3><<<gemm_grid(12544, 768, 8), 256, 0, stream>>>(Pm, wpatch, patch_b, nullptr, h, pos, 12544, 768, 768, 8);
  cls_pos<<<192, 256, 0, stream>>>(cls_tok, pos, h);

  for (int i = 0; i < CL; i++) {
    ln1_kernel<<<3472, 256, 0, stream>>>(h, pr + (size_t)i * 20 * 768, ln1_g + i * 768, ln1_b + i * 768, a_in);
    wtrans<<<dim3(24, 72), dim3(32, 8), 0, stream>>>(qkv_w + (size_t)i * 768 * 2304, wq, 768, 2304);
    gemm_bt<0><<<gemm_grid(13888, 2304, 8), 256, 0, stream>>>(a_in, wq, qkv_b + i * 2304, qkv, nullptr, nullptr, 13888, 2304, 768, 8);
    attn_kernel<<<dim3(12, 64), 256, 0, stream>>>(qkv, advp_w, advp_b, masks + i * CNF, ob);
    wtrans<<<dim3(24, 24), dim3(32, 8), 0, stream>>>(proj_w + (size_t)i * 768 * 768, wp, 768, 768);
    gemm_bt<2><<<gemm_grid(12608, 768, 8), 256, 0, stream>>>(ob, wp, proj_b + i * 768, nullptr, h, nullptr, 12608, 768, 768, 8);
    ln2_kernel<<<3152, 256, 0, stream>>>(h, ln2_g + i * 768, ln2_b + i * 768, mb);
    wtrans<<<dim3(24, 96), dim3(32, 8), 0, stream>>>(fc1_w + (size_t)i * 768 * 3072, w1, 768, 3072);
    gemm_bt<1><<<gemm_grid(12608, 3072, 8), 256, 0, stream>>>(mb, w1, fc1_b + i * 3072, g1, nullptr, nullptr, 12608, 3072, 768, 8);
    wtrans<<<dim3(96, 24), dim3(32, 8), 0, stream>>>(fc2_w + (size_t)i * 3072 * 768, w2, 3072, 768);
    gemm_bt<2><<<gemm_grid(12608, 768, 4), 256, 0, stream>>>(g1, w2, fc2_b + i * 768, nullptr, h, nullptr, 12608, 768, 3072, 4);
  }
  head_kernel<<<64, 256, 0, stream>>>(h, norm_g, norm_b, head_w, head_b, out);
}